// Round 11
// baseline (1457.443 us; speedup 1.0000x reference)
//
#include <hip/hip_runtime.h>

// ---------------------------------------------------------------------------
// TransMIL forward on MI355X.
//   r11: 1673. r12: 1444 (bmm 32x32/512/XCD + ln_pad vec).
//   r13: 1423 — BEST. ln_pad wave-per-row, a3v/out_tile/ppeg XCD pinning.
//   r14: 1452 REGRESSION (qkv LDS-retile: 4.03M bank conflicts, counter-ev).
//   r15: 1442 REGRESSION persists after qkv revert => bmm 16x16/1-wave also
//        bad (no intra-block staging/MFMA overlap). Counter row: qkv 94.8us,
//        MfmaUtil 13%, VALU 17%, HBM 18% => GEMMs ~350 TF, staging-stalled.
//   r16: FULL revert to r13 + ONE change: mfma_tile128 staging via
//        __builtin_amdgcn_global_load_lds width=16 into LINEAR [128][64] LDS
//        (guide ladder m93->m97: 517->874 TF from exactly this swap).
//        Bit-identical math; proj tail rows read in-workspace garbage that
//        feeds only never-stored C rows.
//        (resubmitted verbatim — round 10 was an infra timeout.)
// ---------------------------------------------------------------------------

constexpr int D_    = 512;
constexpr int E_    = 1024;
constexpr int NTOK  = 20737;
constexpr int NP_   = 20992;   // padded seq len (255 zero rows at FRONT)
constexpr int NH_   = 8;
constexpr int HD_   = 64;
constexpr int MLM   = 256;     // landmarks
constexpr int LCH   = 82;      // tokens per landmark
constexpr int HHW   = 144;
constexpr int NFEAT = 20736;   // 144*144
constexpr int PADR  = 255;
constexpr int NCH   = 41;      // a3v N-chunks
constexpr int CHTOK = 512;     // tokens per chunk (8 subchunks of 64)

typedef __attribute__((ext_vector_type(8))) short bf16x8;
typedef __attribute__((ext_vector_type(4))) float f32x4;

__device__ __forceinline__ unsigned short f2bf(float f){
  unsigned int u = __float_as_uint(f);
  unsigned int r = u + 0x7fffu + ((u >> 16) & 1u);
  return (unsigned short)(r >> 16);
}
__device__ __forceinline__ float bfu(unsigned short u){
  return __uint_as_float((unsigned int)u << 16);
}

// async global->LDS, 16 bytes per lane (dest must be wave-uniform base + lane*16)
__device__ __forceinline__ void load_lds16(const unsigned short* g, unsigned short* l){
  __builtin_amdgcn_global_load_lds(
      (const __attribute__((address_space(1))) void*)g,
      (__attribute__((address_space(3))) void*)l, 16, 0, 0);
}

// ---------------- reduction helpers ----------------
__device__ __forceinline__ float waveMaxF(float v){
#pragma unroll
  for (int o = 32; o > 0; o >>= 1) v = fmaxf(v, __shfl_xor(v, o));
  return v;
}
__device__ __forceinline__ float waveSumF(float v){
#pragma unroll
  for (int o = 32; o > 0; o >>= 1) v += __shfl_xor(v, o);
  return v;
}
__device__ __forceinline__ float blockMax256(float v, float* sbuf){
  v = waveMaxF(v);
  if ((threadIdx.x & 63) == 0) sbuf[threadIdx.x >> 6] = v;
  __syncthreads();
  float r = fmaxf(fmaxf(sbuf[0], sbuf[1]), fmaxf(sbuf[2], sbuf[3]));
  __syncthreads();
  return r;
}
__device__ __forceinline__ float blockSum256(float v, float* sbuf){
  v = waveSumF(v);
  if ((threadIdx.x & 63) == 0) sbuf[threadIdx.x >> 6] = v;
  __syncthreads();
  float r = sbuf[0] + sbuf[1] + sbuf[2] + sbuf[3];
  __syncthreads();
  return r;
}

// ---------------- weight prep: W[K][N] fp32 -> Wt[N][K] bf16 ----------------
__global__ __launch_bounds__(256) void wtrans_kernel(
    const float* __restrict__ W, unsigned short* __restrict__ Wt, int K, int N){
  __shared__ float tile[32][33];
  const int kb = blockIdx.x * 32, nb = blockIdx.y * 32;
  const int tx = threadIdx.x, ty = threadIdx.y;
  for (int i = ty; i < 32; i += 8) tile[i][tx] = W[(size_t)(kb + i) * N + nb + tx];
  __syncthreads();
  for (int i = ty; i < 32; i += 8)
    Wt[(size_t)(nb + i) * K + kb + tx] = f2bf(tile[tx][i]);
}

// ---------------- maxpool2 + bf16 ----------------
__global__ __launch_bounds__(256) void pool_bf16_kernel(
    const float* __restrict__ x, unsigned short* __restrict__ Ah){
  size_t idx4 = ((size_t)blockIdx.x * 256 + threadIdx.x) * 4;
  size_t m = idx4 >> 10, e = idx4 & 1023;
  float4 a = *(const float4*)(x + (m * 2) * E_ + e);
  float4 b = *(const float4*)(x + (m * 2 + 1) * E_ + e);
  unsigned long long pk =
      (unsigned long long)f2bf(fmaxf(a.x, b.x))
    | ((unsigned long long)f2bf(fmaxf(a.y, b.y)) << 16)
    | ((unsigned long long)f2bf(fmaxf(a.z, b.z)) << 32)
    | ((unsigned long long)f2bf(fmaxf(a.w, b.w)) << 48);
  *(unsigned long long*)(Ah + idx4) = pk;
}

// ---------------- MFMA 128x128 tile core, BK=64, global_load_lds staging ----
// LDS linear [128][64] (NO padding: global_load_lds writes base+lane*16).
// Chunk c = j*256 + t: LDS shorts [c*8, c*8+8) == row (c>>3), cols (c&7)*8.
// Within a wave c*8 = base + lane*16B exactly. A/B rows must be readable
// (callers guarantee in-allocation; OOB *logical* rows feed only masked C).
__device__ __forceinline__ void mfma_tile128(
    const unsigned short* __restrict__ A, int bm,
    const unsigned short* __restrict__ Bt, int bn, int K,
    f32x4 acc[4][4], unsigned short* As, unsigned short* Bs){
  const int t = threadIdx.x;
  const int lane = t & 63, wave = t >> 6;
  const int wr = wave >> 1, wc = wave & 1;
  const int m16 = lane & 15, quad = lane >> 4;
  for (int kc = 0; kc < K; kc += 64){
#pragma unroll
    for (int j = 0; j < 4; j++){
      int c = j * 256 + t;                 // 0..1023
      int row = c >> 3, off = (c & 7) * 8;
      load_lds16(A  + (size_t)(bm + row) * K + kc + off, As + c * 8);
      load_lds16(Bt + (size_t)(bn + row) * K + kc + off, Bs + c * 8);
    }
    __syncthreads();
#pragma unroll
    for (int k2 = 0; k2 < 64; k2 += 32){
      bf16x8 af[4], bf[4];
#pragma unroll
      for (int mi = 0; mi < 4; mi++)
        af[mi] = *(const bf16x8*)(As + (wr * 64 + mi * 16 + m16) * 64 + k2 + quad * 8);
#pragma unroll
      for (int ni = 0; ni < 4; ni++)
        bf[ni] = *(const bf16x8*)(Bs + (wc * 64 + ni * 16 + m16) * 64 + k2 + quad * 8);
#pragma unroll
      for (int mi = 0; mi < 4; mi++)
#pragma unroll
        for (int ni = 0; ni < 4; ni++)
          acc[mi][ni] = __builtin_amdgcn_mfma_f32_16x16x32_bf16(af[mi], bf[ni], acc[mi][ni], 0, 0, 0);
    }
    __syncthreads();
  }
}

// ---------------- fc1 (grid 160x4: 160*128 == 20480 rows exactly) -----------
__global__ __launch_bounds__(256) void fc1_mfma_kernel(
    const unsigned short* __restrict__ Ah, const unsigned short* __restrict__ Bt,
    const float* __restrict__ bias, float* __restrict__ h){
  __shared__ unsigned short As[128 * 64], Bs[128 * 64];
  f32x4 z4 = {0.f, 0.f, 0.f, 0.f};
  f32x4 acc[4][4];
#pragma unroll
  for (int i = 0; i < 4; i++)
#pragma unroll
    for (int j = 0; j < 4; j++) acc[i][j] = z4;
  const int bm = blockIdx.x * 128, bn = blockIdx.y * 128;
  mfma_tile128(Ah, bm, Bt, bn, E_, acc, As, Bs);
  const int lane = threadIdx.x & 63, wave = threadIdx.x >> 6;
  const int wr = wave >> 1, wc = wave & 1;
  const int m16 = lane & 15, quad = lane >> 4;
#pragma unroll
  for (int mi = 0; mi < 4; mi++)
#pragma unroll
    for (int ni = 0; ni < 4; ni++){
      int col = bn + wc * 64 + ni * 16 + m16;
      float bv = bias[col];
#pragma unroll
      for (int r = 0; r < 4; r++){
        int row = bm + wr * 64 + mi * 16 + quad * 4 + r;
        float vv = fmaxf(acc[mi][ni][r] + bv, 0.f);
        h[(size_t)(1 + row) * D_ + col] = vv;
        if (row < 256) h[(size_t)(20481 + row) * D_ + col] = vv;
      }
    }
}

__global__ void cls_kernel(const float* __restrict__ cls, float* __restrict__ h){
  int c = blockIdx.x * 256 + threadIdx.x;
  if (c < D_) h[c] = cls[c];
}

__global__ void row0_copy_kernel(const float* __restrict__ src, float* __restrict__ dst){
  int c = blockIdx.x * 256 + threadIdx.x;
  if (c < D_) dst[c] = src[c];
}

// ---------------- layernorm -> zero-padded bf16 xph (wave-per-row) ----------
__global__ __launch_bounds__(256) void ln_pad_kernel(
    const float* __restrict__ h, const float* __restrict__ w,
    const float* __restrict__ b, unsigned short* __restrict__ xph){
  const int wv = threadIdx.x >> 6, lane = threadIdx.x & 63;
  const int r = blockIdx.x * 4 + wv;
  unsigned int* xp32 = (unsigned int*)xph;
  if (r < PADR){
    uint4 z = {0u, 0u, 0u, 0u};
    *(uint4*)(xp32 + (size_t)r * 256 + lane * 4) = z;
    return;
  }
  const float* x = h + (size_t)(r - PADR) * D_;
  float4 a0 = *(const float4*)(x + lane * 8);
  float4 a1 = *(const float4*)(x + lane * 8 + 4);
  float s = (a0.x + a0.y) + (a0.z + a0.w) + (a1.x + a1.y) + (a1.z + a1.w);
  float mu = waveSumF(s) * (1.f / 512.f);
  float d[8] = {a0.x - mu, a0.y - mu, a0.z - mu, a0.w - mu,
                a1.x - mu, a1.y - mu, a1.z - mu, a1.w - mu};
  float vs = 0.f;
#pragma unroll
  for (int i = 0; i < 8; i++) vs += d[i] * d[i];
  float var = waveSumF(vs) * (1.f / 512.f);
  float rs = rsqrtf(var + 1e-5f);
  float4 w0 = *(const float4*)(w + lane * 8);
  float4 w1 = *(const float4*)(w + lane * 8 + 4);
  float4 b0 = *(const float4*)(b + lane * 8);
  float4 b1 = *(const float4*)(b + lane * 8 + 4);
  float wv8[8] = {w0.x, w0.y, w0.z, w0.w, w1.x, w1.y, w1.z, w1.w};
  float bv8[8] = {b0.x, b0.y, b0.z, b0.w, b1.x, b1.y, b1.z, b1.w};
  uint4 pk;
  unsigned int* pkp = (unsigned int*)&pk;
#pragma unroll
  for (int i = 0; i < 4; i++){
    unsigned int lo = f2bf(d[2 * i] * rs * wv8[2 * i] + bv8[2 * i]);
    unsigned int hi = f2bf(d[2 * i + 1] * rs * wv8[2 * i + 1] + bv8[2 * i + 1]);
    pkp[i] = lo | (hi << 16);
  }
  *(uint4*)(xp32 + (size_t)r * 256 + lane * 4) = pk;
}

// ---------------- qkv MFMA (grid 164x12: 164*128 == 20992 == NP_ exactly) ---
__global__ __launch_bounds__(256) void qkv_mfma_kernel(
    const unsigned short* __restrict__ A, const unsigned short* __restrict__ Bt,
    unsigned short* __restrict__ q16, unsigned short* __restrict__ k16,
    unsigned short* __restrict__ v16){
  __shared__ unsigned short As[128 * 64], Bs[128 * 64];
  f32x4 z4 = {0.f, 0.f, 0.f, 0.f};
  f32x4 acc[4][4];
#pragma unroll
  for (int i = 0; i < 4; i++)
#pragma unroll
    for (int j = 0; j < 4; j++) acc[i][j] = z4;
  const int bm = blockIdx.x * 128, bn = blockIdx.y * 128;
  mfma_tile128(A, bm, Bt, bn, D_, acc, As, Bs);
  const int lane = threadIdx.x & 63, wave = threadIdx.x >> 6;
  const int wr = wave >> 1, wc = wave & 1;
  const int m16 = lane & 15, quad = lane >> 4;
#pragma unroll
  for (int mi = 0; mi < 4; mi++)
#pragma unroll
    for (int ni = 0; ni < 4; ni++){
      int col = bn + wc * 64 + ni * 16 + m16;
      int which = col >> 9, hh = (col >> 6) & 7, d = col & 63;
      size_t cbase = (size_t)hh * NP_ * HD_ + d;
      unsigned short* dst;
      float sc = 1.f;
      if (which == 0){ dst = q16; sc = 0.125f; }
      else if (which == 1) dst = k16;
      else dst = v16;
#pragma unroll
      for (int r = 0; r < 4; r++){
        int row = bm + wr * 64 + mi * 16 + quad * 4 + r;
        dst[cbase + (size_t)row * HD_] = f2bf(acc[mi][ni][r] * sc);
      }
    }
}

// ---------------- landmarks (wave-per-landmark, 4 per block) ----------------
__global__ __launch_bounds__(256) void landmark_kernel(
    const unsigned short* __restrict__ q16, const unsigned short* __restrict__ k16,
    float* __restrict__ ql, float* __restrict__ kl,
    unsigned short* __restrict__ qlh, unsigned short* __restrict__ klh){
  const int wv = threadIdx.x >> 6, d = threadIdx.x & 63;
  const int im = blockIdx.x * 4 + wv, h = blockIdx.y;
  size_t base = ((size_t)h * NP_ + (size_t)im * LCH) * HD_ + d;
  float sq = 0.f, sk = 0.f;
  for (int r = 0; r < LCH; r++){
    sq += bfu(q16[base + (size_t)r * HD_]);
    sk += bfu(k16[base + (size_t)r * HD_]);
  }
  float qm = sq * (1.f / 82.f), km = sk * (1.f / 82.f);
  size_t oidx = ((size_t)h * MLM + im) * HD_ + d;
  ql[oidx] = qm;  qlh[oidx] = f2bf(qm);
  kl[oidx] = km;  klh[oidx] = f2bf(km);
}

// ---------------- a2 = softmax(ql @ kl^T); also split-bf16 materialized ------
__global__ __launch_bounds__(256) void a2_kernel(
    const float* __restrict__ ql, const float* __restrict__ kl,
    float* __restrict__ a2, unsigned short* __restrict__ a2h,
    unsigned short* __restrict__ a2l){
  const int im = blockIdx.x, h = blockIdx.y, t = threadIdx.x;
  __shared__ __align__(16) float qs[64];
  __shared__ float s4[4];
  if (t < 64) qs[t] = ql[((size_t)h * MLM + im) * HD_ + t];
  __syncthreads();
  const float4* kr4 = (const float4*)(kl + ((size_t)h * MLM + t) * HD_);
  const float4* qs4 = (const float4*)qs;
  float s = 0.f;
#pragma unroll
  for (int d4 = 0; d4 < 16; d4++){
    float4 kv = kr4[d4], qv = qs4[d4];
    s += qv.x*kv.x + qv.y*kv.y + qv.z*kv.z + qv.w*kv.w;
  }
  float mx = blockMax256(s, s4);
  float e = __expf(s - mx);
  float S = blockSum256(e, s4);
  float v = e / S;
  size_t idx = ((size_t)h * MLM + im) * MLM + t;
  a2[idx] = v;
  unsigned short hi = f2bf(v);
  a2h[idx] = hi;
  a2l[idx] = f2bf(v - bfu(hi));
}

// ---------------- pinv scale: col-sum max only (rows of softmax sum to 1) ----
__global__ __launch_bounds__(256) void pinv_scale_kernel(
    const float* __restrict__ a2, float* __restrict__ scal){
  const int h = blockIdx.x, j = threadIdx.x;
  const float* A = a2 + (size_t)h * MLM * MLM;
  float cs = 0.f;
  for (int t = 0; t < MLM; t++) cs += A[(size_t)t * MLM + j];
  __shared__ float s4[4];
  float cmax = blockMax256(cs, s4);
  if (j == 0) scal[h] = cmax;
}

// z0 = a2^T * inv, materialized as split-bf16 row-major AND transposed
__global__ __launch_bounds__(256) void pinv_init_kernel(
    const float* __restrict__ a2, const float* __restrict__ scal,
    unsigned short* __restrict__ zh, unsigned short* __restrict__ zl,
    unsigned short* __restrict__ zth, unsigned short* __restrict__ ztl){
  const int i = blockIdx.x, h = blockIdx.y, j = threadIdx.x;
  float cmax = scal[0];
#pragma unroll
  for (int hh = 1; hh < 8; hh++) cmax = fmaxf(cmax, scal[hh]);
  float inv = 1.f / cmax;          // rmax == 1 exactly (softmax rows)
  size_t idx = ((size_t)h * MLM + i) * MLM + j;
  float vr = a2[((size_t)h * MLM + j) * MLM + i] * inv;  // z0[i][j]
  float vt = a2[idx] * inv;                              // z0T[i][j] = z0[j][i]
  unsigned short hi = f2bf(vr);
  zh[idx] = hi; zl[idx] = f2bf(vr - bfu(hi));
  hi = f2bf(vt);
  zth[idx] = hi; ztl[idx] = f2bf(vt - bfu(hi));
}

// ---------------- batched 256^3 split-bf16 MFMA on pre-split operands --------
// 32x32 tiles, 1D grid of 512 blocks, head = bid&7 => XCD affinity.
// B_eff[k][n] = c0*I[k==n] + Bt[n][k]. C = c1 * A @ B_eff.
__global__ __launch_bounds__(256) void bmm256_split_kernel(
    const unsigned short* __restrict__ Ahg, const unsigned short* __restrict__ Alg,
    const unsigned short* __restrict__ Bthg, const unsigned short* __restrict__ Btlg,
    float c0, float c1,
    unsigned short* __restrict__ Crh, unsigned short* __restrict__ Crl,
    unsigned short* __restrict__ Cth, unsigned short* __restrict__ Ctl,
    float* __restrict__ Cf, unsigned int tsgn){
  __shared__ __align__(16) unsigned short Ash[32 * 72], Asl[32 * 72];
  __shared__ __align__(16) unsigned short Bsh[32 * 72], Bsl[32 * 72];
  const int bid = blockIdx.x;
  const int h = bid & 7;               // XCD affinity
  const int tid2 = bid >> 3;           // 0..63
  const int bm = (tid2 & 7) * 32;
  const int bn = (tid2 >> 3) * 32;
  const int t = threadIdx.x, lane = t & 63, w = t >> 6;
  const int wr = w >> 1, wc = w & 1, m16 = lane & 15, quad = lane >> 4;
  const size_t hb = (size_t)h * 65536;
  const unsigned short* gAh0 = Ahg + hb + (size_t)bm * 256;
  const unsigned short* gAl0 = Alg + hb + (size_t)bm * 256;
  const unsigned short* gBh0 = Bthg + hb + (size_t)bn * 256;
  const unsigned short* gBl0 = Btlg + hb + (size_t)bn * 256;
  const int srow = t >> 3, soff = (t & 7) * 8;       // staging: 32 rows x 64 k
  const int sl = srow * 72 + soff;
  f32x4 acc = {0.f, 0.f, 0.f, 0.f};
  for (int kc = 0; kc < 256; kc += 64){
    {
      size_t g = (size_t)srow * 256 + kc + soff;
      *(uint4*)(Ash + sl) = *(const uint4*)(gAh0 + g);
      *(uint4*)(Asl + sl) = *(const uint4*)(gAl0 + g);
      *(uint4*)(Bsh + sl) = *(const uint4*)(gBh0 + g);
      *(uint4*)(Bsl + sl) = *(const uint4*)(gBl0 + g);
    }
    __syncthreads();
    if (c0 != 0.f && (bn & ~63) == kc){
      // diagonal patch: B_eff diag = c0 + stored; resplit (32 elems, in-window)
      if (t < 32){
        int kloc = bn - kc + t;        // n = bn+t, k = n, local k index
        float v = c0 + bfu(Bsh[t * 72 + kloc]) + bfu(Bsl[t * 72 + kloc]);
        unsigned short hi = f2bf(v);
        Bsh[t * 72 + kloc] = hi;
        Bsl[t * 72 + kloc] = f2bf(v - bfu(hi));
      }
      __syncthreads();
    }
#pragma unroll
    for (int k2 = 0; k2 < 64; k2 += 32){
      bf16x8 ah = *(const bf16x8*)(Ash + (wr * 16 + m16) * 72 + k2 + quad * 8);
      bf16x8 al = *(const bf16x8*)(Asl + (wr * 16 + m16) * 72 + k2 + quad * 8);
      bf16x8 bh = *(const bf16x8*)(Bsh + (wc * 16 + m16) * 72 + k2 + quad * 8);
      bf16x8 bl = *(const bf16x8*)(Bsl + (wc * 16 + m16) * 72 + k2 + quad * 8);
      acc = __builtin_amdgcn_mfma_f32_16x16x32_bf16(ah, bh, acc, 0, 0, 0);
      acc = __builtin_amdgcn_mfma_f32_16x16x32_bf16(ah, bl, acc, 0, 0, 0);
      acc = __builtin_amdgcn_mfma_f32_16x16x32_bf16(al, bh, acc, 0, 0, 0);
    }
    __syncthreads();
  }
#pragma unroll
  for (int r = 0; r < 4; r++){
    int row = bm + wr * 16 + quad * 4 + r;
    int col = bn + wc * 16 + m16;
    float v = c1 * acc[r];
    unsigned short hi = f2bf(v);
    unsigned short lo = f2bf(v - bfu(hi));
    size_t rm = hb + (size_t)row * 256 + col;
    if (Crh){ Crh[rm] = hi; Crl[rm] = lo; }
    if (Cth){
      size_t tm = hb + (size_t)col * 256 + row;
      Cth[tm] = hi ^ (unsigned short)tsgn;
      Ctl[tm] = lo ^ (unsigned short)tsgn;
    }
    if (Cf) Cf[rm] = v;
  }
}

// ---------------- a3v split-K flash, bf16 MFMA (XCD-pinned 1D grid) ---------
__global__ __launch_bounds__(256) void a3v_part_kernel(
    const unsigned short* __restrict__ qlh, const unsigned short* __restrict__ k16,
    const unsigned short* __restrict__ v16, float* __restrict__ pacc,
    float* __restrict__ pml){
  __shared__ __align__(16) unsigned short qs16[64 * 72];
  __shared__ __align__(16) unsigned short kb16[64 * 72];   // K, then P
  __shared__ __align__(16) unsigned short vt16[64 * 72];   // V^T [d][n]
  const int bid = blockIdx.x;
  const int h = bid & 7;
  const int j = bid >> 3;
  const int lt = j & 3;
  const int ch = j >> 2;
  const int t = threadIdx.x;
  const int lane = t & 63, w = t >> 6;
  const int m16 = lane & 15, quad = lane >> 4;

  const unsigned short* qg = qlh + ((size_t)h * MLM + lt * 64) * HD_;
  for (int idx = t; idx < 512; idx += 256){
    int row = idx >> 3, off = (idx & 7) * 8;
    *(uint4*)(qs16 + row * 72 + off) = *(const uint4*)(qg + (size_t)row * HD_ + off);
  }
  f32x4 z4 = {0.f, 0.f, 0.f, 0.f};
  f32x4 acc_o[4] = {z4, z4, z4, z4};
  float mreg[4], lreg[4];
#pragma unroll
  for (int r = 0; r < 4; r++){ mreg[r] = -3.0e38f; lreg[r] = 0.f; }
  const unsigned short* kg = k16 + ((size_t)h * NP_ + ch * CHTOK) * HD_;
  const unsigned short* vg = v16 + ((size_t)h * NP_ + ch * CHTOK) * HD_;

  for (int sc = 0; sc < 8; sc++){
    __syncthreads();
    for (int idx = t; idx < 512; idx += 256){
      int row = idx >> 3, off = (idx & 7) * 8;
      *(uint4*)(kb16 + row * 72 + off) =
          *(const uint4*)(kg + (size_t)(sc * 64 + row) * HD_ + off);
      uint4 pv = *(const uint4*)(vg + (size_t)(sc * 64 + row) * HD_ + off);
      unsigned int uu[4] = {pv.x, pv.y, pv.z, pv.w};
#pragma unroll
      for (int jj = 0; jj < 4; jj++){
        vt16[(off + 2 * jj)     * 72 + row] = (unsigned short)(uu[jj] & 0xffffu);
        vt16[(off + 2 * jj + 1) * 72 + row] = (unsigned short)(uu[jj] >> 16);
      }
    }
    __syncthreads();
    f32x4 acc_s[4] = {z4, z4, z4, z4};
#pragma unroll
    for (int kc = 0; kc < 64; kc += 32){
      bf16x8 a = *(const bf16x8*)(qs16 + (w * 16 + m16) * 72 + kc + quad * 8);
#pragma unroll
      for (int ni = 0; ni < 4; ni++){
        bf16x8 b = *(const bf16x8*)(kb16 + (ni * 16 + m16) * 72 + kc + quad * 8);
        acc_s[ni] = __builtin_amdgcn_mfma_f32_16x16x32_bf16(a, b, acc_s[ni], 0, 0, 0);
      }
    }
    __syncthreads();
#pragma unroll
    for (int r = 0; r < 4; r++){
      float cm = fmaxf(fmaxf(acc_s[0][r], acc_s[1][r]), fmaxf(acc_s[2][r], acc_s[3][r]));
#pragma unroll
      for (int o = 1; o < 16; o <<= 1) cm = fmaxf(cm, __shfl_xor(cm, o));
      // exact defer-max: skipping the rescale when no row grew is mult-by-1.0
      if (__any(cm > mreg[r])){
        float mn = fmaxf(mreg[r], cm);
        float scl = __expf(mreg[r] - mn);
        lreg[r] *= scl;
        acc_o[0][r] *= scl; acc_o[1][r] *= scl;
        acc_o[2][r] *= scl; acc_o[3][r] *= scl;
        mreg[r] = mn;
      }
      float mcur = mreg[r];
      float p0 = __expf(acc_s[0][r] - mcur), p1 = __expf(acc_s[1][r] - mcur);
      float p2 = __expf(acc_s[2][r] - mcur), p3 = __expf(acc_s[3][r] - mcur);
      float ls = (p0 + p1) + (p2 + p3);
#pragma unroll
      for (int o = 1; o < 16; o <<= 1) ls += __shfl_xor(ls, o);
      lreg[r] += ls;
      int prow = (w * 16 + quad * 4 + r) * 72 + m16;
      kb16[prow + 0]  = f2bf(p0);
      kb16[prow + 16] = f2bf(p1);
      kb16[prow + 32] = f2bf(p2);
      kb16[prow + 48] = f2bf(p3);
    }
    __syncthreads();
#pragma unroll
    for (int kc = 0; kc < 64; kc += 32){
      bf16x8 a = *(const bf16x8*)(kb16 + (w * 16 + m16) * 72 + kc + quad * 8);
#pragma unroll
      for (int ni = 0; ni < 4; ni++){
        bf16x8 b = *(const bf16x8*)(vt16 + (ni * 16 + m16) * 72 + kc + quad * 8);
        acc_o[ni] = __builtin_amdgcn_mfma_f32_16x16x32_bf16(a, b, acc_o[ni], 0, 0, 0);
      }
    }
  }
#pragma unroll
  for (int r = 0; r < 4; r++){
    int im = lt * 64 + w * 16 + quad * 4 + r;
    size_t base = ((size_t)h * NCH + ch) * MLM + im;
#pragma unroll
    for (int ni = 0; ni < 4; ni++)
      pacc[base * HD_ + ni * 16 + m16] = acc_o[ni][r];
    if (m16 == 0){
      pml[base * 2]     = mreg[r];
      pml[base * 2 + 1] = lreg[r];
    }
  }
}

__global__ __launch_bounds__(64) void a3v_combine_kernel(
    const float* __restrict__ pacc, const float* __restrict__ pml,
    float* __restrict__ t1){
  const int im = blockIdx.x, h = blockIdx.y, lane = threadIdx.x;
  float M = -3.0e38f;
  for (int c = 0; c < NCH; c++)
    M = fmaxf(M, pml[(((size_t)h * NCH + c) * MLM + im) * 2]);
  float accv = 0.f, L = 0.f;
  for (int c = 0; c < NCH; c++){
    size_t base = ((size_t)h * NCH + c) * MLM + im;
    float mc = pml[base * 2], lc = pml[base * 2 + 1];
    float w = __expf(mc - M);
    accv += w * pacc[base * HD_ + lane];
    L += w * lc;
  }
  t1[((size_t)h * MLM + im) * HD_ + lane] = accv / L;
}

// ---------------- t2^T = (z @ t1)^T, bf16 [h][d][im] ----------------
__global__ __launch_bounds__(256) void zt1_kernel(
    const float* __restrict__ z, const float* __restrict__ t1,
    unsigned short* __restrict__ t2t){
  const int h = blockIdx.y;
  const int t = threadIdx.x;
  const int d = t & 63, ri = t >> 6;
  const int im = blockIdx.x * 4 + ri;
  const float* zr = z + ((size_t)h * MLM + im) * MLM;
  const float* t1h = t1 + (size_t)h * MLM * HD_;
  float acc = 0.f;
#pragma unroll 8
  for (int kk = 0; kk < MLM; kk++) acc += zr[kk] * t1h[(size_t)kk * HD_ + d];
  t2t[((size_t)h * HD_ + d) * MLM + im] = f2bf(acc);
}

// ---------------- out tile MFMA: 64 tokens x 1 head per block ----------------
__global__ __launch_bounds__(256) void out_tile_kernel(
    const unsigned short* __restrict__ q16, const unsigned short* __restrict__ klh,
    const unsigned short* __restrict__ t2t, const unsigned short* __restrict__ v16,
    const float* __restrict__ resw, unsigned short* __restrict__ outh){
  __shared__ __align__(16) unsigned short smem[64 * 72 * 2 + 64 * 264];
  unsigned short* qs16 = smem;                 // 64 x 72
  unsigned short* kb16 = smem + 64 * 72;       // 64 x 72 (kl chunks, t2t chunks)
  unsigned short* Ps   = smem + 64 * 72 * 2;   // 64 x 264 (P bf16; later O f32 + v tile)
  const int bid = blockIdx.x;
  const int h = bid & 7, tile = bid >> 3;
  const int n0 = PADR + tile * 64;
  const int t = threadIdx.x;
  const int lane = t & 63, w = t >> 6;
  const int m16 = lane & 15, quad = lane >> 4;

  {
    const unsigned short* qh = q16 + (size_t)h * NP_ * HD_;
    for (int idx = t; idx < 512; idx += 256){
      int row = idx >> 3, off = (idx & 7) * 8;
      int n = n0 + row;
      uint4 val = {0u, 0u, 0u, 0u};
      if (n < NP_) val = *(const uint4*)(qh + (size_t)n * HD_ + off);
      *(uint4*)(qs16 + row * 72 + off) = val;
    }
  }
  f32x4 z4 = {0.f, 0.f, 0.f, 0.f};
  f32x4 acc_s[16];
#pragma unroll
  for (int i = 0; i < 16; i++) acc_s[i] = z4;
  const unsigned short* klg = klh + (size_t)h * MLM * HD_;
  for (int m = 0; m < 4; m++){
    __syncthreads();
    for (int idx = t; idx < 512; idx += 256){
      int row = idx >> 3, off = (idx & 7) * 8;
      *(uint4*)(kb16 + row * 72 + off) =
          *(const uint4*)(klg + (size_t)(m * 64 + row) * HD_ + off);
    }
    __syncthreads();
#pragma unroll
    for (int kc = 0; kc < 64; kc += 32){
      bf16x8 a = *(const bf16x8*)(qs16 + (w * 16 + m16) * 72 + kc + quad * 8);
#pragma unroll
      for (int ni = 0; ni < 4; ni++){
        bf16x8 b = *(const bf16x8*)(kb16 + (ni * 16 + m16) * 72 + kc + quad * 8);
        acc_s[m * 4 + ni] = __builtin_amdgcn_mfma_f32_16x16x32_bf16(a, b, acc_s[m * 4 + ni], 0, 0, 0);
      }
    }
  }
  __syncthreads();
#pragma unroll
  for (int r = 0; r < 4; r++){
    float mx = acc_s[0][r];
#pragma unroll
    for (int mc = 1; mc < 16; mc++) mx = fmaxf(mx, acc_s[mc][r]);
#pragma unroll
    for (int o = 1; o < 16; o <<= 1) mx = fmaxf(mx, __shfl_xor(mx, o));
    float p[16]; float sum = 0.f;
#pragma unroll
    for (int mc = 0; mc < 16; mc++){ p[mc] = __expf(acc_s[mc][r] - mx); sum += p[mc]; }
#pragma unroll
    for (int o = 1; o < 16; o <<= 1) sum += __shfl_xor(sum, o);
    float inv = 1.f / sum;
    int prow = (w * 16 + quad * 4 + r) * 264;
#pragma unroll
    for (int mc = 0; mc < 16; mc++)
      Ps[prow + (mc >> 2) * 64 + (mc & 3) * 16 + m16] = f2bf(p[mc] * inv);
  }
  f32x4 acc_o[4] = {z4, z4, z4, z4};
  const unsigned short* t2g = t2t + (size_t)h * HD_ * MLM;
  for (int ch = 0; ch < 4; ch++){
    __syncthreads();
    {
      int row = t >> 2, c8 = (t & 3) * 16;
      const unsigned short* src = t2g + (size_t)row * MLM + ch * 64 + c8;
      *(uint4*)(kb16 + row * 72 + c8)     = *(const uint4*)src;
      *(uint4*)(kb16 + row * 72 + c8 + 8) = *(const uint4*)(src + 8);
    }
    __syncthreads();
#pragma unroll
    for (int kc = 0; kc < 64; kc += 32){
      bf16x8 a = *(const bf16x8*)(Ps + (w * 16 + m16) * 264 + ch * 64 + kc + quad * 8);
#pragma unroll
      for (int ni = 0; ni < 4; ni++){
        bf16x8 b = *(const bf16x8*)(kb16 + (ni * 16 + m16) * 72 + kc + quad * 8);
        acc_o[ni] = __builtin_amdgcn_mfma_f32_16x16x32_bf16(a, b, acc_o[ni], 0, 0, 0);
      }
    }
  }
  __syncthreads();
  float* Obuf = (float*)Ps;                          // 64 x 66 f32
  unsigned short* vtile = (unsigned short*)(Obuf + 64 * 66);  // 96 x 72 bf16
#pragma unroll
  for (int r = 0; r < 4; r++){
    int row = w * 16 + quad * 4 + r;
#pragma unroll
    for (int ni = 0; ni < 4; ni++)
      Obuf[row * 66 + ni * 16 + m16] = acc_o[ni][r];
  }
  {
    const unsigned short* vh = v16 + (size_t)h * NP_ * HD_;
    for (int idx = t; idx < 768; idx += 256){
      int row = idx >> 3, off = (idx & 7) * 8;
      int nn = n0 - 16 + row;
      uint4 val = {0u, 0u, 0u, 0u};
      if (nn < NP_) val = *(const uint4*)(vh + (size_t)nn * HD_ + off);
      *(uint4*)(vtile + row * 72 + off) = val;
    }
  }
  __syncthreads();
  float wreg[33];
  {
    const float* wr = resw + h * 33;
#pragma unroll
    for (int kk = 0; kk < 33; kk++) wreg[kk] = wr[kk];
  }
  const int ty = t >> 4, tx = t & 15;
#pragma unroll
  for (int i = 0; i < 4; i++){
    int lrow = ty * 4 + i;
    float c0v = 0.f, c1v = 0.f, c2v = 0.f, c3v = 0.f;
    for (int kk = 0; kk < 33; kk++){
      uint2 uv = *(const uint2*)(vtile + (lrow + kk) * 72 + tx * 4);
      float wv = wreg[kk];
      c0v += __uint_as_float(uv.x << 16) * wv;
      c1v += __uint_as_float(uv.x & 0xffff0000u) * wv;
      c2v += __uint_as_float(uv.y << 16) * wv;
      c3v += __uint_as_float(uv.y & 0xffff0000u) * wv;
    }
    int trow = tile * 64 + lrow;
    if (trow < NTOK){
      const float* orow = Obuf + lrow * 66 + tx * 4;
      unsigned long long pk =
          (unsigned long long)f2bf(orow[0] + c0v)
        | ((unsigned long long)f2bf(orow[1] + c1v) << 16)
        | ((unsigned long long)f2bf(orow[2] + c2v) << 32)
        | ((unsigned long long)f2bf(orow[3] + c3v) << 48);
      *(unsigned long long*)(outh + (size_t)trow * D_ + h * HD_ + tx * 4) = pk;
    }
  }
}

// ---------------- proj MFMA: h += outh @ out_wt^T + bias ----------------
// A rows beyond NTOK (up to 20864) read in-workspace garbage; their C rows
// are masked at store. B grid exact (512).
__global__ __launch_bounds__(256) void proj_mfma_kernel(
    const unsigned short* __restrict__ A, const unsigned short* __restrict__ Bt,
    const float* __restrict__ bias, float* __restrict__ h){
  __shared__ unsigned short As[128 * 64], Bs[128 * 64];
  f32x4 z4 = {0.f, 0.f, 0.f, 0.f};
  f32x4 acc[4][4];
#pragma unroll
  for (int i = 0; i < 4; i++)
#pragma unroll
    for (int j = 0; j < 4; j++) acc[i][j] = z4;
  const int bm = blockIdx.x * 128, bn = blockIdx.y * 128;
  mfma_tile128(A, bm, Bt, bn, D_, acc, As, Bs);
  const int lane = threadIdx.x & 63, wave = threadIdx.x >> 6;
  const int wr = wave >> 1, wc = wave & 1;
  const int m16 = lane & 15, quad = lane >> 4;
#pragma unroll
  for (int mi = 0; mi < 4; mi++)
#pragma unroll
    for (int ni = 0; ni < 4; ni++){
      int col = bn + wc * 64 + ni * 16 + m16;
      float bv = bias[col];
#pragma unroll
      for (int r = 0; r < 4; r++){
        int row = bm + wr * 64 + mi * 16 + quad * 4 + r;
        if (row < NTOK) h[(size_t)row * D_ + col] += acc[mi][ni][r] + bv;
      }
    }
}

// ---------------- PPEG ----------------
__global__ __launch_bounds__(512) void ppeg_combine_kernel(
    const float* __restrict__ w7, const float* __restrict__ b7,
    const float* __restrict__ w5, const float* __restrict__ b5,
    const float* __restrict__ w3, const float* __restrict__ b3,
    float* __restrict__ wcomb, float* __restrict__ bcomb){
  const int c = threadIdx.x;
#pragma unroll
  for (int i = 0; i < 7; i++){
#pragma unroll
    for (int j = 0; j < 7; j++){
      int di = i - 3, dj = j - 3;
      float wv = w7[(size_t)c * 49 + i * 7 + j];
      if (di >= -2 && di <= 2 && dj >= -2 && dj <= 2)
        wv += w5[(size_t)c * 25 + (di + 2) * 5 + (dj + 2)];
      if (di >= -1 && di <= 1 && dj >= -1 && dj <= 1)
        wv += w3[(size_t)c * 9 + (di + 1) * 3 + (dj + 1)];
      if (di == 0 && dj == 0) wv += 1.f;
      wcomb[(size_t)(i * 7 + j) * 512 + c] = wv;
    }
  }
  bcomb[c] = b7[c] + b5[c] + b3[c];
}

// y-banded XCD map: xcd = bid&7 owns rows [xcd*18, xcd*18+18)
__global__ __launch_bounds__(512) void ppeg_conv_kernel(
    const float* __restrict__ h, const float* __restrict__ wcomb,
    const float* __restrict__ bcomb, float* __restrict__ h2){
  const int c = threadIdx.x;
  const int bid = blockIdx.x;
  const int xcd = bid & 7;
  const int idx = bid >> 3;          // 0..323
  const int y = xcd * 18 + idx / 18;
  const int x0 = (idx % 18) * 8;
  float wc[49];
#pragma unroll
  for (int kk = 0; kk < 49; kk++) wc[kk] = wcomb[(size_t)kk * 512 + c];
  float acc[8];
  const float bv = bcomb[c];
#pragma unroll
  for (int p = 0; p < 8; p++) acc[p] = bv;
#pragma unroll
  for (int i = 0; i < 7; i++){
    const int yy = y + i - 3;
    if (yy < 0 || yy >= HHW) continue;
    const float* hrow = h + (size_t)(1 + yy * HHW) * D_ + c;
    float line[14];
#pragma unroll
    for (int j = 0; j < 14; j++){
      const int xx = x0 + j - 3;
      line[j] = (xx >= 0 && xx < HHW) ? hrow[(size_t)xx * D_] : 0.f;
    }
#pragma unroll
    for (int p = 0; p < 8; p++)
#pragma unroll
      for (int j = 0; j < 7; j++)
        acc[p] += line[p + j] * wc[i * 7 + j];
  }
#pragma unroll
  for (int p = 0; p < 8; p++)
    h2[(size_t)(1 + y * HHW + x0 + p) * D_ + c] = acc[p];
}

// ---------------- final ----------------
__global__ __launch_bounds__(512) void final_kernel(
    const float* __restrict__ h, const float* __restrict__ w,
    const float* __restrict__ b, const float* __restrict__ fc3w,
    const float* __restrict__ fc3b, float* __restrict__ out){
  __shared__ float vec[512];
  __shared__ float s8[8];
  __shared__ float lg[4];
  const int t = threadIdx.x;
  float x = h[t];
  float v = waveSumF(x);
  if ((t & 63) == 0) s8[t >> 6] = v;
  __syncthreads();
  float sum = 0.f;
#pragma unroll
  for (int i = 0; i < 8; i++) sum += s8[i];
  float mu = sum * (1.f / 512.f);
  __syncthreads();
  float d = x - mu;
  v = waveSumF(d * d);
  if ((t & 63) == 0) s8[t >> 6] = v;
  __syncthreads();
  float var = 0.f;
#pragma unroll
  for (int i = 0; i < 8; i++) var += s8[i];
  var *= (1.f / 512.f);
  float rs = rsqrtf(var + 1e-5f);
  vec[t] = d * rs * w[t] + b[t];
  __syncthreads();
  if (t < 4){
    float acc = fc3b[t];
    for (int kk = 0; kk < 512; kk++) acc += vec[kk] * fc3w[kk * 4 + t];
    lg[t] = acc;
  }
  __syncthreads();
  if (t == 0){
    float m = fmaxf(fmaxf(lg[0], lg[1]), fmaxf(lg[2], lg[3]));
    float e[4], se = 0.f;
#pragma unroll
    for (int i = 0; i < 4; i++){ e[i] = __expf(lg[i] - m); se += e[i]; }
    int am = 0; float bm = lg[0];
#pragma unroll
    for (int i = 1; i < 4; i++) if (lg[i] > bm){ bm = lg[i]; am = i; }
#pragma unroll
    for (int i = 0; i < 4; i++){ out[i] = lg[i]; out[4 + i] = e[i] / se; }
    out[8] = (float)am;
  }
}

// ---------------------------------------------------------------------------
extern "C" void kernel_launch(void* const* d_in, const int* in_sizes, int n_in,
                              void* d_out, int out_size, void* d_ws, size_t ws_size,
                              hipStream_t stream) {
  const float* x       = (const float*)d_in[0];
  const float* fc1_w   = (const float*)d_in[1];
  const float* fc1_b   = (const float*)d_in[2];
  const float* cls_tok = (const float*)d_in[3];
  const float* l1_nw   = (const float*)d_in[4];
  const float* l1_nb   = (const float*)d_in[5];
  const float* l1_qkvw = (const float*)d_in[6];
  const float* l1_outw = (const float*)d_in[7];
  const float* l1_outb = (const float*)d_in[8];
  const float* l1_resw = (const float*)d_in[9];
  const float* ppeg_w7 = (const float*)d_in[10];
  const float* ppeg_b7 = (const float*)d_in[11];
  const float* ppeg_w5 = (const float*)d_in[12];
  const float* ppeg_b5 = (const float*)d_in[13];
  const float* ppeg_w3 = (const float*)d_in[14];
  const float* ppeg_b3 = (const float*)d_in[15];
  const float* l2_nw   = (const float*)d_in[16];
  const float* l2_nb   = (const float*)d_in[17];
  const float* l2_qkvw = (const float*)d_in[18];
  const float* l2_outw = (const float*)d_in[19];
  const float* l2_outb = (const float*)d_in[20];
  const float* l2_resw = (const float*)d_in[21];
  const float* norm_w  = (const float*)d_in[22];
  const float* norm_b  = (const float*)d_in[23];
  const float* fc3_w   = (const float*)d_in[24];
  const float* fc3_b   = (const float*)d_in[25];

  // workspace layout (float units)
  float* W = (float*)d_ws;
  size_t o = 0;
  float* hbuf = W + o; o += (size_t)NTOK * D_;
  float* xp   = W + o; o += (size_t)NP_ * D_;   // xph / pacc+pml / outh
  float* qb   = W + o; o += (size_t)NH_ * NP_ * HD_;   // bf16 q; also Ah pre-layer
  float* kb   = W + o; o += (size_t)NH_ * NP_ * HD_;   // bf16 k
  float* vb   = W + o; o += (size_t)NH_ * NP_ * HD_;   // bf16 v
  float* qlb  = W + o; o += (size_t)NH_ * MLM * HD_;
  float* klb  = W + o; o += (size_t)NH_ * MLM * HD_;
  float* a2b  = W + o; o += (size_t)NH_ * MLM * MLM;
  float* zfin = W + o; o += (size_t)NH_ * MLM * MLM;   // final z fp32 (zt1 input)
  float* t1b  = W + o; o += (size_t)NH_ * MLM * HD_;
  float* t2r  = W + o; o += (size_t)NH_ * MLM * HD_;   // t2t bf16 lives here
  float* scalf = W + o; o += 16;
  float* wcomb = W + o; o += 49 * 512;
  float* bcomb = W + o; o += 512;
  unsigned short* fc1_wt  = (unsigned short*)(W + o); o += (size_t)D_ * E_ / 2;
  unsigned short* qkv_wt1 = (unsigned short*)(W + o); o += (size_t)1536 * D_ / 2;
  unsigned short* qkv_wt2 = (unsigned short*)(W + o); o += (size_t)1536 * D_ / 2;
  unsigned short* out_wt1 = (unsigned short*)(W + o); o += (size_t)D_ * D_ / 2;
  unsigned short* out_wt2 = (unsigned short*)(W + o); o += (size_t)D_ * D_ / 2;
  unsigned short* qlh = (unsigned short*)(W + o); o += (size_t)NH_ * MLM * HD_ / 2;
  unsigned short* klh = (unsigned short*)(W + o); o += (size_t)NH_ * MLM * HD_ / 2;
  // pinv split-bf16 arrays: 18 x [NH][256][256] ushorts
  const size_t HM = (size_t)NH_ * MLM * MLM;
  unsigned short* usp = (unsigned short*)(W + o); o += 18 * HM / 2;
  unsigned short* a2sh  = usp; usp += HM;
  unsigned short* a2sl  = usp; usp += HM;
  unsigned short* tah_s = usp; usp += HM;
  unsigned short* tal_s = usp; usp += HM;
  unsigned short* tath_s = usp; usp += HM;
  unsigned short* tatl_s = usp; usp += HM;
  unsigned short* tbth_s = usp; usp += HM;
  unsigned short* tbtl_s = usp; usp += HM;
  unsigned short* tcth_s = usp; usp += HM;
  unsigned short* tctl_s = usp; usp += HM;
  unsigned short* zsh[2], *zsl[2], *zsth[2], *zstl[2];
  for (int s = 0; s < 2; s++){
    zsh[s]  = usp; usp += HM;
    zsl[s]  = usp; usp += HM;
    zsth[s] = usp; usp += HM;
    zstl[s] = usp; usp += HM;
  }
  float* hbuf2 = W + o; o += (size_t)NTOK * D_;       // ppeg ping-pong target

  unsigned short* xph = (unsigned short*)xp;
  float* pacc = xp;
  float* pml  = xp + (size_t)NH_ * NCH * MLM * HD_;
  unsigned short* outh = (unsigned short*)xp;
  unsigned short* Ah  = (unsigned short*)qb;
  unsigned short* q16 = (unsigned short*)qb;
  unsigned short* k16 = (unsigned short*)kb;
  unsigned short* v16 = (unsigned short*)vb;
  unsigned short* t2t = (unsigned short*)t2r;

  // ---- weight prep (once per launch) ----
  wtrans_kernel<<<dim3(E_ / 32, D_ / 32), dim3(32, 8), 0, stream>>>(fc1_w, fc1_wt, E_, D_);
  wtrans_kernel<<<dim3(D_ / 32, 1536 / 32), dim3(32, 8), 0, stream>>>(l1_qkvw, qkv_wt1, D_, 1536);
  wtrans_kernel<<<dim3(D_ / 32, 1536 / 32), dim3(32, 8), 0, stream>>>(l2_qkvw, qkv_wt2, D_, 1536);
  wtrans_kernel<<<dim3(D_ / 32, D_ / 32), dim3(32, 8), 0, stream>>>(l1_outw, out_wt1, D_, D_);
  wtrans_kernel<<<dim3(D_ / 32, D_ / 32), dim3(32, 8), 0, stream>>>(l2_outw, out_wt2, D_, D_);
  ppeg_combine_kernel<<<1, 512, 0, stream>>>(ppeg_w7, ppeg_b7, ppeg_w5, ppeg_b5,
                                             ppeg_w3, ppeg_b3, wcomb, bcomb);

  // ---- fc1 (maxpool -> bf16 -> MFMA 128-tile) ----
  pool_bf16_kernel<<<20480, 256, 0, stream>>>(x, Ah);
  fc1_mfma_kernel<<<dim3(160, 4), 256, 0, stream>>>(Ah, fc1_wt, fc1_b, hbuf);
  cls_kernel<<<2, 256, 0, stream>>>(cls_tok, hbuf);

  auto run_layer = [&](float* hcur, const float* nw, const float* nb,
                       const unsigned short* qkvwt, const unsigned short* outwt,
                       const float* outb, const float* resw){
    ln_pad_kernel<<<NP_ / 4, 256, 0, stream>>>(hcur, nw, nb, xph);
    qkv_mfma_kernel<<<dim3(164, 12), 256, 0, stream>>>(xph, qkvwt, q16, k16, v16);
    landmark_kernel<<<dim3(64, 8), 256, 0, stream>>>(q16, k16, qlb, klb, qlh, klh);
    a2_kernel<<<dim3(256, 8), 256, 0, stream>>>(qlb, klb, a2b, a2sh, a2sl);
    pinv_scale_kernel<<<8, 256, 0, stream>>>(a2b, scalf);
    pinv_init_kernel<<<dim3(256, 8), 256, 0, stream>>>(a2b, scalf,
        zsh[0], zsl[0], zsth[0], zstl[0]);
    int c = 0;
    for (int it = 0; it < 6; it++){
      // ta = a2 @ z                  (RM for A-use; -ta^T for B-use)
      bmm256_split_kernel<<<512, 256, 0, stream>>>(
          a2sh, a2sl, zsth[c], zstl[c], 0.f, 1.f,
          tah_s, tal_s, tath_s, tatl_s, nullptr, 0x8000u);
      // tb = ta @ (7I - ta)          (-tb^T only)
      bmm256_split_kernel<<<512, 256, 0, stream>>>(
          tah_s, tal_s, tath_s, tatl_s, 7.f, 1.f,
          nullptr, nullptr, tbth_s, tbtl_s, nullptr, 0x8000u);
      // tc = ta @ (15I - tb)         (-tc^T only)
      bmm256_split_kernel<<<512, 256, 0, stream>>>(
          tah_s, tal_s, tbth_s, tbtl_s, 15.f, 1.f,
          nullptr, nullptr, tcth_s, tctl_s, nullptr, 0x8000u);
      // z' = 0.25 * z @ (13I - tc)   (RM + +z'^T; fp32 on last iter)
      bmm256_split_kernel<<<512, 256, 0, stream>>>(
          zsh[c], zsl[c], tcth_s, tctl_s, 13.f, 0.25f,
          zsh[c ^ 1], zsl[c ^ 1], zsth[c ^ 1], zstl[c ^ 1],
          (it == 5) ? zfin : nullptr, 0u);
      c ^= 1;
    }
    a3v_part_kernel<<<NCH * 32, 256, 0, stream>>>(qlh, k16, v16, pacc, pml);
    a3v_combine_kernel<<<dim3(256, 8), 64, 0, stream>>>(pacc, pml, t1b);
    zt1_kernel<<<dim3(64, 8), 256, 0, stream>>>(zfin, t1b, t2t);
    out_tile_kernel<<<325 * 8, 256, 0, stream>>>(q16, klh, t2t, v16, resw, outh);
    proj_mfma_kernel<<<dim3(163, 4), 256, 0, stream>>>(outh, outwt, outb, hcur);
  };

  run_layer(hbuf, l1_nw, l1_nb, qkv_wt1, out_wt1, l1_outb, l1_resw);
  // PPEG: conv writes rows 1.. of hbuf2 directly; cls row copied
  ppeg_conv_kernel<<<2592, 512, 0, stream>>>(hbuf, wcomb, bcomb, hbuf2);
  row0_copy_kernel<<<2, 256, 0, stream>>>(hbuf, hbuf2);
  run_layer(hbuf2, l2_nw, l2_nb, qkv_wt2, out_wt2, l2_outb, l2_resw);
  final_kernel<<<1, 512, 0, stream>>>(hbuf2, norm_w, norm_b, fc3_w, fc3_b, (float*)d_out);
}

// Round 14
// 1437.955 us; speedup vs baseline: 1.0136x; 1.0136x over previous
//
#include <hip/hip_runtime.h>

// ---------------------------------------------------------------------------
// TransMIL forward on MI355X.
//   r13: 1423 — BEST (ln_pad wave-per-row, XCD pinning everywhere).
//   r14: 1452 REG (qkv LDS-retile: 4M bank conflicts). r15: 1442 REG
//        (bmm 16x16/1-wave). r16: 1457 REG — gload_lds linear [128][64]:
//        fragment reads = 16 lanes x same column x 128B row pitch = 16-way
//        LDS read conflict (G4); staging gain eaten by self-inflicted
//        conflicts. absmax unchanged => addressing was correct.
//   r17: r16 + BOTH-sides XOR swizzle (rule #21 / T2): linear LDS dest,
//        pre-swizzled global SOURCE (soff = (s^(row&7))*8), swizzled READ
//        (col' = col ^ ((row&7)<<3)). Bit-identical; read conflicts 16->2-way.
//        (resubmitted verbatim x2 — rounds 12 and 13 were infra timeouts.)
// ---------------------------------------------------------------------------

constexpr int D_    = 512;
constexpr int E_    = 1024;
constexpr int NTOK  = 20737;
constexpr int NP_   = 20992;   // padded seq len (255 zero rows at FRONT)
constexpr int NH_   = 8;
constexpr int HD_   = 64;
constexpr int MLM   = 256;     // landmarks
constexpr int LCH   = 82;      // tokens per landmark
constexpr int HHW   = 144;
constexpr int NFEAT = 20736;   // 144*144
constexpr int PADR  = 255;
constexpr int NCH   = 41;      // a3v N-chunks
constexpr int CHTOK = 512;     // tokens per chunk (8 subchunks of 64)

typedef __attribute__((ext_vector_type(8))) short bf16x8;
typedef __attribute__((ext_vector_type(4))) float f32x4;

__device__ __forceinline__ unsigned short f2bf(float f){
  unsigned int u = __float_as_uint(f);
  unsigned int r = u + 0x7fffu + ((u >> 16) & 1u);
  return (unsigned short)(r >> 16);
}
__device__ __forceinline__ float bfu(unsigned short u){
  return __uint_as_float((unsigned int)u << 16);
}

// async global->LDS, 16 bytes per lane (dest must be wave-uniform base + lane*16)
__device__ __forceinline__ void load_lds16(const unsigned short* g, unsigned short* l){
  __builtin_amdgcn_global_load_lds(
      (const __attribute__((address_space(1))) void*)g,
      (__attribute__((address_space(3))) void*)l, 16, 0, 0);
}

// ---------------- reduction helpers ----------------
__device__ __forceinline__ float waveMaxF(float v){
#pragma unroll
  for (int o = 32; o > 0; o >>= 1) v = fmaxf(v, __shfl_xor(v, o));
  return v;
}
__device__ __forceinline__ float waveSumF(float v){
#pragma unroll
  for (int o = 32; o > 0; o >>= 1) v += __shfl_xor(v, o);
  return v;
}
__device__ __forceinline__ float blockMax256(float v, float* sbuf){
  v = waveMaxF(v);
  if ((threadIdx.x & 63) == 0) sbuf[threadIdx.x >> 6] = v;
  __syncthreads();
  float r = fmaxf(fmaxf(sbuf[0], sbuf[1]), fmaxf(sbuf[2], sbuf[3]));
  __syncthreads();
  return r;
}
__device__ __forceinline__ float blockSum256(float v, float* sbuf){
  v = waveSumF(v);
  if ((threadIdx.x & 63) == 0) sbuf[threadIdx.x >> 6] = v;
  __syncthreads();
  float r = sbuf[0] + sbuf[1] + sbuf[2] + sbuf[3];
  __syncthreads();
  return r;
}

// ---------------- weight prep: W[K][N] fp32 -> Wt[N][K] bf16 ----------------
__global__ __launch_bounds__(256) void wtrans_kernel(
    const float* __restrict__ W, unsigned short* __restrict__ Wt, int K, int N){
  __shared__ float tile[32][33];
  const int kb = blockIdx.x * 32, nb = blockIdx.y * 32;
  const int tx = threadIdx.x, ty = threadIdx.y;
  for (int i = ty; i < 32; i += 8) tile[i][tx] = W[(size_t)(kb + i) * N + nb + tx];
  __syncthreads();
  for (int i = ty; i < 32; i += 8)
    Wt[(size_t)(nb + i) * K + kb + tx] = f2bf(tile[tx][i]);
}

// ---------------- maxpool2 + bf16 ----------------
__global__ __launch_bounds__(256) void pool_bf16_kernel(
    const float* __restrict__ x, unsigned short* __restrict__ Ah){
  size_t idx4 = ((size_t)blockIdx.x * 256 + threadIdx.x) * 4;
  size_t m = idx4 >> 10, e = idx4 & 1023;
  float4 a = *(const float4*)(x + (m * 2) * E_ + e);
  float4 b = *(const float4*)(x + (m * 2 + 1) * E_ + e);
  unsigned long long pk =
      (unsigned long long)f2bf(fmaxf(a.x, b.x))
    | ((unsigned long long)f2bf(fmaxf(a.y, b.y)) << 16)
    | ((unsigned long long)f2bf(fmaxf(a.z, b.z)) << 32)
    | ((unsigned long long)f2bf(fmaxf(a.w, b.w)) << 48);
  *(unsigned long long*)(Ah + idx4) = pk;
}

// ---------------- MFMA 128x128 tile core, BK=64, gload_lds + XOR swizzle ----
// Linear LDS dest; SOURCE pre-swizzled: chunk (row, s) fetches global subcol
// (s ^ (row&7)); READ applies the same involution: col' = col ^ ((row&7)<<3).
// LDS[row*64 + x] holds global[row][x ^ ((row&7)<<3)] (shorts). Bit-identical.
__device__ __forceinline__ void mfma_tile128(
    const unsigned short* __restrict__ A, int bm,
    const unsigned short* __restrict__ Bt, int bn, int K,
    f32x4 acc[4][4], unsigned short* As, unsigned short* Bs){
  const int t = threadIdx.x;
  const int lane = t & 63, wave = t >> 6;
  const int wr = wave >> 1, wc = wave & 1;
  const int m16 = lane & 15, quad = lane >> 4;
  const int sw = (m16 & 7) << 3;       // read-side XOR (row&7)<<3, row%8==m16%8
  for (int kc = 0; kc < K; kc += 64){
#pragma unroll
    for (int j = 0; j < 4; j++){
      int c = j * 256 + t;                 // 0..1023
      int row = c >> 3, s = c & 7;
      int soff = ((s ^ (row & 7)) * 8);    // pre-swizzled source subcol
      load_lds16(A  + (size_t)(bm + row) * K + kc + soff, As + c * 8);
      load_lds16(Bt + (size_t)(bn + row) * K + kc + soff, Bs + c * 8);
    }
    __syncthreads();
#pragma unroll
    for (int k2 = 0; k2 < 64; k2 += 32){
      bf16x8 af[4], bf[4];
#pragma unroll
      for (int mi = 0; mi < 4; mi++)
        af[mi] = *(const bf16x8*)(As + (wr * 64 + mi * 16 + m16) * 64
                                     + ((k2 + quad * 8) ^ sw));
#pragma unroll
      for (int ni = 0; ni < 4; ni++)
        bf[ni] = *(const bf16x8*)(Bs + (wc * 64 + ni * 16 + m16) * 64
                                     + ((k2 + quad * 8) ^ sw));
#pragma unroll
      for (int mi = 0; mi < 4; mi++)
#pragma unroll
        for (int ni = 0; ni < 4; ni++)
          acc[mi][ni] = __builtin_amdgcn_mfma_f32_16x16x32_bf16(af[mi], bf[ni], acc[mi][ni], 0, 0, 0);
    }
    __syncthreads();
  }
}

// ---------------- fc1 (grid 160x4: 160*128 == 20480 rows exactly) -----------
__global__ __launch_bounds__(256) void fc1_mfma_kernel(
    const unsigned short* __restrict__ Ah, const unsigned short* __restrict__ Bt,
    const float* __restrict__ bias, float* __restrict__ h){
  __shared__ unsigned short As[128 * 64], Bs[128 * 64];
  f32x4 z4 = {0.f, 0.f, 0.f, 0.f};
  f32x4 acc[4][4];
#pragma unroll
  for (int i = 0; i < 4; i++)
#pragma unroll
    for (int j = 0; j < 4; j++) acc[i][j] = z4;
  const int bm = blockIdx.x * 128, bn = blockIdx.y * 128;
  mfma_tile128(Ah, bm, Bt, bn, E_, acc, As, Bs);
  const int lane = threadIdx.x & 63, wave = threadIdx.x >> 6;
  const int wr = wave >> 1, wc = wave & 1;
  const int m16 = lane & 15, quad = lane >> 4;
#pragma unroll
  for (int mi = 0; mi < 4; mi++)
#pragma unroll
    for (int ni = 0; ni < 4; ni++){
      int col = bn + wc * 64 + ni * 16 + m16;
      float bv = bias[col];
#pragma unroll
      for (int r = 0; r < 4; r++){
        int row = bm + wr * 64 + mi * 16 + quad * 4 + r;
        float vv = fmaxf(acc[mi][ni][r] + bv, 0.f);
        h[(size_t)(1 + row) * D_ + col] = vv;
        if (row < 256) h[(size_t)(20481 + row) * D_ + col] = vv;
      }
    }
}

__global__ void cls_kernel(const float* __restrict__ cls, float* __restrict__ h){
  int c = blockIdx.x * 256 + threadIdx.x;
  if (c < D_) h[c] = cls[c];
}

__global__ void row0_copy_kernel(const float* __restrict__ src, float* __restrict__ dst){
  int c = blockIdx.x * 256 + threadIdx.x;
  if (c < D_) dst[c] = src[c];
}

// ---------------- layernorm -> zero-padded bf16 xph (wave-per-row) ----------
__global__ __launch_bounds__(256) void ln_pad_kernel(
    const float* __restrict__ h, const float* __restrict__ w,
    const float* __restrict__ b, unsigned short* __restrict__ xph){
  const int wv = threadIdx.x >> 6, lane = threadIdx.x & 63;
  const int r = blockIdx.x * 4 + wv;
  unsigned int* xp32 = (unsigned int*)xph;
  if (r < PADR){
    uint4 z = {0u, 0u, 0u, 0u};
    *(uint4*)(xp32 + (size_t)r * 256 + lane * 4) = z;
    return;
  }
  const float* x = h + (size_t)(r - PADR) * D_;
  float4 a0 = *(const float4*)(x + lane * 8);
  float4 a1 = *(const float4*)(x + lane * 8 + 4);
  float s = (a0.x + a0.y) + (a0.z + a0.w) + (a1.x + a1.y) + (a1.z + a1.w);
  float mu = waveSumF(s) * (1.f / 512.f);
  float d[8] = {a0.x - mu, a0.y - mu, a0.z - mu, a0.w - mu,
                a1.x - mu, a1.y - mu, a1.z - mu, a1.w - mu};
  float vs = 0.f;
#pragma unroll
  for (int i = 0; i < 8; i++) vs += d[i] * d[i];
  float var = waveSumF(vs) * (1.f / 512.f);
  float rs = rsqrtf(var + 1e-5f);
  float4 w0 = *(const float4*)(w + lane * 8);
  float4 w1 = *(const float4*)(w + lane * 8 + 4);
  float4 b0 = *(const float4*)(b + lane * 8);
  float4 b1 = *(const float4*)(b + lane * 8 + 4);
  float wv8[8] = {w0.x, w0.y, w0.z, w0.w, w1.x, w1.y, w1.z, w1.w};
  float bv8[8] = {b0.x, b0.y, b0.z, b0.w, b1.x, b1.y, b1.z, b1.w};
  uint4 pk;
  unsigned int* pkp = (unsigned int*)&pk;
#pragma unroll
  for (int i = 0; i < 4; i++){
    unsigned int lo = f2bf(d[2 * i] * rs * wv8[2 * i] + bv8[2 * i]);
    unsigned int hi = f2bf(d[2 * i + 1] * rs * wv8[2 * i + 1] + bv8[2 * i + 1]);
    pkp[i] = lo | (hi << 16);
  }
  *(uint4*)(xp32 + (size_t)r * 256 + lane * 4) = pk;
}

// ---------------- qkv MFMA (grid 164x12: 164*128 == 20992 == NP_ exactly) ---
__global__ __launch_bounds__(256) void qkv_mfma_kernel(
    const unsigned short* __restrict__ A, const unsigned short* __restrict__ Bt,
    unsigned short* __restrict__ q16, unsigned short* __restrict__ k16,
    unsigned short* __restrict__ v16){
  __shared__ unsigned short As[128 * 64], Bs[128 * 64];
  f32x4 z4 = {0.f, 0.f, 0.f, 0.f};
  f32x4 acc[4][4];
#pragma unroll
  for (int i = 0; i < 4; i++)
#pragma unroll
    for (int j = 0; j < 4; j++) acc[i][j] = z4;
  const int bm = blockIdx.x * 128, bn = blockIdx.y * 128;
  mfma_tile128(A, bm, Bt, bn, D_, acc, As, Bs);
  const int lane = threadIdx.x & 63, wave = threadIdx.x >> 6;
  const int wr = wave >> 1, wc = wave & 1;
  const int m16 = lane & 15, quad = lane >> 4;
#pragma unroll
  for (int mi = 0; mi < 4; mi++)
#pragma unroll
    for (int ni = 0; ni < 4; ni++){
      int col = bn + wc * 64 + ni * 16 + m16;
      int which = col >> 9, hh = (col >> 6) & 7, d = col & 63;
      size_t cbase = (size_t)hh * NP_ * HD_ + d;
      unsigned short* dst;
      float sc = 1.f;
      if (which == 0){ dst = q16; sc = 0.125f; }
      else if (which == 1) dst = k16;
      else dst = v16;
#pragma unroll
      for (int r = 0; r < 4; r++){
        int row = bm + wr * 64 + mi * 16 + quad * 4 + r;
        dst[cbase + (size_t)row * HD_] = f2bf(acc[mi][ni][r] * sc);
      }
    }
}

// ---------------- landmarks (wave-per-landmark, 4 per block) ----------------
__global__ __launch_bounds__(256) void landmark_kernel(
    const unsigned short* __restrict__ q16, const unsigned short* __restrict__ k16,
    float* __restrict__ ql, float* __restrict__ kl,
    unsigned short* __restrict__ qlh, unsigned short* __restrict__ klh){
  const int wv = threadIdx.x >> 6, d = threadIdx.x & 63;
  const int im = blockIdx.x * 4 + wv, h = blockIdx.y;
  size_t base = ((size_t)h * NP_ + (size_t)im * LCH) * HD_ + d;
  float sq = 0.f, sk = 0.f;
  for (int r = 0; r < LCH; r++){
    sq += bfu(q16[base + (size_t)r * HD_]);
    sk += bfu(k16[base + (size_t)r * HD_]);
  }
  float qm = sq * (1.f / 82.f), km = sk * (1.f / 82.f);
  size_t oidx = ((size_t)h * MLM + im) * HD_ + d;
  ql[oidx] = qm;  qlh[oidx] = f2bf(qm);
  kl[oidx] = km;  klh[oidx] = f2bf(km);
}

// ---------------- a2 = softmax(ql @ kl^T); also split-bf16 materialized ------
__global__ __launch_bounds__(256) void a2_kernel(
    const float* __restrict__ ql, const float* __restrict__ kl,
    float* __restrict__ a2, unsigned short* __restrict__ a2h,
    unsigned short* __restrict__ a2l){
  const int im = blockIdx.x, h = blockIdx.y, t = threadIdx.x;
  __shared__ __align__(16) float qs[64];
  __shared__ float s4[4];
  if (t < 64) qs[t] = ql[((size_t)h * MLM + im) * HD_ + t];
  __syncthreads();
  const float4* kr4 = (const float4*)(kl + ((size_t)h * MLM + t) * HD_);
  const float4* qs4 = (const float4*)qs;
  float s = 0.f;
#pragma unroll
  for (int d4 = 0; d4 < 16; d4++){
    float4 kv = kr4[d4], qv = qs4[d4];
    s += qv.x*kv.x + qv.y*kv.y + qv.z*kv.z + qv.w*kv.w;
  }
  float mx = blockMax256(s, s4);
  float e = __expf(s - mx);
  float S = blockSum256(e, s4);
  float v = e / S;
  size_t idx = ((size_t)h * MLM + im) * MLM + t;
  a2[idx] = v;
  unsigned short hi = f2bf(v);
  a2h[idx] = hi;
  a2l[idx] = f2bf(v - bfu(hi));
}

// ---------------- pinv scale: col-sum max only (rows of softmax sum to 1) ----
__global__ __launch_bounds__(256) void pinv_scale_kernel(
    const float* __restrict__ a2, float* __restrict__ scal){
  const int h = blockIdx.x, j = threadIdx.x;
  const float* A = a2 + (size_t)h * MLM * MLM;
  float cs = 0.f;
  for (int t = 0; t < MLM; t++) cs += A[(size_t)t * MLM + j];
  __shared__ float s4[4];
  float cmax = blockMax256(cs, s4);
  if (j == 0) scal[h] = cmax;
}

// z0 = a2^T * inv, materialized as split-bf16 row-major AND transposed
__global__ __launch_bounds__(256) void pinv_init_kernel(
    const float* __restrict__ a2, const float* __restrict__ scal,
    unsigned short* __restrict__ zh, unsigned short* __restrict__ zl,
    unsigned short* __restrict__ zth, unsigned short* __restrict__ ztl){
  const int i = blockIdx.x, h = blockIdx.y, j = threadIdx.x;
  float cmax = scal[0];
#pragma unroll
  for (int hh = 1; hh < 8; hh++) cmax = fmaxf(cmax, scal[hh]);
  float inv = 1.f / cmax;          // rmax == 1 exactly (softmax rows)
  size_t idx = ((size_t)h * MLM + i) * MLM + j;
  float vr = a2[((size_t)h * MLM + j) * MLM + i] * inv;  // z0[i][j]
  float vt = a2[idx] * inv;                              // z0T[i][j] = z0[j][i]
  unsigned short hi = f2bf(vr);
  zh[idx] = hi; zl[idx] = f2bf(vr - bfu(hi));
  hi = f2bf(vt);
  zth[idx] = hi; ztl[idx] = f2bf(vt - bfu(hi));
}

// ---------------- batched 256^3 split-bf16 MFMA on pre-split operands --------
// 32x32 tiles, 1D grid of 512 blocks, head = bid&7 => XCD affinity.
// B_eff[k][n] = c0*I[k==n] + Bt[n][k]. C = c1 * A @ B_eff.
__global__ __launch_bounds__(256) void bmm256_split_kernel(
    const unsigned short* __restrict__ Ahg, const unsigned short* __restrict__ Alg,
    const unsigned short* __restrict__ Bthg, const unsigned short* __restrict__ Btlg,
    float c0, float c1,
    unsigned short* __restrict__ Crh, unsigned short* __restrict__ Crl,
    unsigned short* __restrict__ Cth, unsigned short* __restrict__ Ctl,
    float* __restrict__ Cf, unsigned int tsgn){
  __shared__ __align__(16) unsigned short Ash[32 * 72], Asl[32 * 72];
  __shared__ __align__(16) unsigned short Bsh[32 * 72], Bsl[32 * 72];
  const int bid = blockIdx.x;
  const int h = bid & 7;               // XCD affinity
  const int tid2 = bid >> 3;           // 0..63
  const int bm = (tid2 & 7) * 32;
  const int bn = (tid2 >> 3) * 32;
  const int t = threadIdx.x, lane = t & 63, w = t >> 6;
  const int wr = w >> 1, wc = w & 1, m16 = lane & 15, quad = lane >> 4;
  const size_t hb = (size_t)h * 65536;
  const unsigned short* gAh0 = Ahg + hb + (size_t)bm * 256;
  const unsigned short* gAl0 = Alg + hb + (size_t)bm * 256;
  const unsigned short* gBh0 = Bthg + hb + (size_t)bn * 256;
  const unsigned short* gBl0 = Btlg + hb + (size_t)bn * 256;
  const int srow = t >> 3, soff = (t & 7) * 8;       // staging: 32 rows x 64 k
  const int sl = srow * 72 + soff;
  f32x4 acc = {0.f, 0.f, 0.f, 0.f};
  for (int kc = 0; kc < 256; kc += 64){
    {
      size_t g = (size_t)srow * 256 + kc + soff;
      *(uint4*)(Ash + sl) = *(const uint4*)(gAh0 + g);
      *(uint4*)(Asl + sl) = *(const uint4*)(gAl0 + g);
      *(uint4*)(Bsh + sl) = *(const uint4*)(gBh0 + g);
      *(uint4*)(Bsl + sl) = *(const uint4*)(gBl0 + g);
    }
    __syncthreads();
    if (c0 != 0.f && (bn & ~63) == kc){
      // diagonal patch: B_eff diag = c0 + stored; resplit (32 elems, in-window)
      if (t < 32){
        int kloc = bn - kc + t;        // n = bn+t, k = n, local k index
        float v = c0 + bfu(Bsh[t * 72 + kloc]) + bfu(Bsl[t * 72 + kloc]);
        unsigned short hi = f2bf(v);
        Bsh[t * 72 + kloc] = hi;
        Bsl[t * 72 + kloc] = f2bf(v - bfu(hi));
      }
      __syncthreads();
    }
#pragma unroll
    for (int k2 = 0; k2 < 64; k2 += 32){
      bf16x8 ah = *(const bf16x8*)(Ash + (wr * 16 + m16) * 72 + k2 + quad * 8);
      bf16x8 al = *(const bf16x8*)(Asl + (wr * 16 + m16) * 72 + k2 + quad * 8);
      bf16x8 bh = *(const bf16x8*)(Bsh + (wc * 16 + m16) * 72 + k2 + quad * 8);
      bf16x8 bl = *(const bf16x8*)(Bsl + (wc * 16 + m16) * 72 + k2 + quad * 8);
      acc = __builtin_amdgcn_mfma_f32_16x16x32_bf16(ah, bh, acc, 0, 0, 0);
      acc = __builtin_amdgcn_mfma_f32_16x16x32_bf16(ah, bl, acc, 0, 0, 0);
      acc = __builtin_amdgcn_mfma_f32_16x16x32_bf16(al, bh, acc, 0, 0, 0);
    }
    __syncthreads();
  }
#pragma unroll
  for (int r = 0; r < 4; r++){
    int row = bm + wr * 16 + quad * 4 + r;
    int col = bn + wc * 16 + m16;
    float v = c1 * acc[r];
    unsigned short hi = f2bf(v);
    unsigned short lo = f2bf(v - bfu(hi));
    size_t rm = hb + (size_t)row * 256 + col;
    if (Crh){ Crh[rm] = hi; Crl[rm] = lo; }
    if (Cth){
      size_t tm = hb + (size_t)col * 256 + row;
      Cth[tm] = hi ^ (unsigned short)tsgn;
      Ctl[tm] = lo ^ (unsigned short)tsgn;
    }
    if (Cf) Cf[rm] = v;
  }
}

// ---------------- a3v split-K flash, bf16 MFMA (XCD-pinned 1D grid) ---------
__global__ __launch_bounds__(256) void a3v_part_kernel(
    const unsigned short* __restrict__ qlh, const unsigned short* __restrict__ k16,
    const unsigned short* __restrict__ v16, float* __restrict__ pacc,
    float* __restrict__ pml){
  __shared__ __align__(16) unsigned short qs16[64 * 72];
  __shared__ __align__(16) unsigned short kb16[64 * 72];   // K, then P
  __shared__ __align__(16) unsigned short vt16[64 * 72];   // V^T [d][n]
  const int bid = blockIdx.x;
  const int h = bid & 7;
  const int j = bid >> 3;
  const int lt = j & 3;
  const int ch = j >> 2;
  const int t = threadIdx.x;
  const int lane = t & 63, w = t >> 6;
  const int m16 = lane & 15, quad = lane >> 4;

  const unsigned short* qg = qlh + ((size_t)h * MLM + lt * 64) * HD_;
  for (int idx = t; idx < 512; idx += 256){
    int row = idx >> 3, off = (idx & 7) * 8;
    *(uint4*)(qs16 + row * 72 + off) = *(const uint4*)(qg + (size_t)row * HD_ + off);
  }
  f32x4 z4 = {0.f, 0.f, 0.f, 0.f};
  f32x4 acc_o[4] = {z4, z4, z4, z4};
  float mreg[4], lreg[4];
#pragma unroll
  for (int r = 0; r < 4; r++){ mreg[r] = -3.0e38f; lreg[r] = 0.f; }
  const unsigned short* kg = k16 + ((size_t)h * NP_ + ch * CHTOK) * HD_;
  const unsigned short* vg = v16 + ((size_t)h * NP_ + ch * CHTOK) * HD_;

  for (int sc = 0; sc < 8; sc++){
    __syncthreads();
    for (int idx = t; idx < 512; idx += 256){
      int row = idx >> 3, off = (idx & 7) * 8;
      *(uint4*)(kb16 + row * 72 + off) =
          *(const uint4*)(kg + (size_t)(sc * 64 + row) * HD_ + off);
      uint4 pv = *(const uint4*)(vg + (size_t)(sc * 64 + row) * HD_ + off);
      unsigned int uu[4] = {pv.x, pv.y, pv.z, pv.w};
#pragma unroll
      for (int jj = 0; jj < 4; jj++){
        vt16[(off + 2 * jj)     * 72 + row] = (unsigned short)(uu[jj] & 0xffffu);
        vt16[(off + 2 * jj + 1) * 72 + row] = (unsigned short)(uu[jj] >> 16);
      }
    }
    __syncthreads();
    f32x4 acc_s[4] = {z4, z4, z4, z4};
#pragma unroll
    for (int kc = 0; kc < 64; kc += 32){
      bf16x8 a = *(const bf16x8*)(qs16 + (w * 16 + m16) * 72 + kc + quad * 8);
#pragma unroll
      for (int ni = 0; ni < 4; ni++){
        bf16x8 b = *(const bf16x8*)(kb16 + (ni * 16 + m16) * 72 + kc + quad * 8);
        acc_s[ni] = __builtin_amdgcn_mfma_f32_16x16x32_bf16(a, b, acc_s[ni], 0, 0, 0);
      }
    }
    __syncthreads();
#pragma unroll
    for (int r = 0; r < 4; r++){
      float cm = fmaxf(fmaxf(acc_s[0][r], acc_s[1][r]), fmaxf(acc_s[2][r], acc_s[3][r]));
#pragma unroll
      for (int o = 1; o < 16; o <<= 1) cm = fmaxf(cm, __shfl_xor(cm, o));
      // exact defer-max: skipping the rescale when no row grew is mult-by-1.0
      if (__any(cm > mreg[r])){
        float mn = fmaxf(mreg[r], cm);
        float scl = __expf(mreg[r] - mn);
        lreg[r] *= scl;
        acc_o[0][r] *= scl; acc_o[1][r] *= scl;
        acc_o[2][r] *= scl; acc_o[3][r] *= scl;
        mreg[r] = mn;
      }
      float mcur = mreg[r];
      float p0 = __expf(acc_s[0][r] - mcur), p1 = __expf(acc_s[1][r] - mcur);
      float p2 = __expf(acc_s[2][r] - mcur), p3 = __expf(acc_s[3][r] - mcur);
      float ls = (p0 + p1) + (p2 + p3);
#pragma unroll
      for (int o = 1; o < 16; o <<= 1) ls += __shfl_xor(ls, o);
      lreg[r] += ls;
      int prow = (w * 16 + quad * 4 + r) * 72 + m16;
      kb16[prow + 0]  = f2bf(p0);
      kb16[prow + 16] = f2bf(p1);
      kb16[prow + 32] = f2bf(p2);
      kb16[prow + 48] = f2bf(p3);
    }
    __syncthreads();
#pragma unroll
    for (int kc = 0; kc < 64; kc += 32){
      bf16x8 a = *(const bf16x8*)(kb16 + (w * 16 + m16) * 72 + kc + quad * 8);
#pragma unroll
      for (int ni = 0; ni < 4; ni++){
        bf16x8 b = *(const bf16x8*)(vt16 + (ni * 16 + m16) * 72 + kc + quad * 8);
        acc_o[ni] = __builtin_amdgcn_mfma_f32_16x16x32_bf16(a, b, acc_o[ni], 0, 0, 0);
      }
    }
  }
#pragma unroll
  for (int r = 0; r < 4; r++){
    int im = lt * 64 + w * 16 + quad * 4 + r;
    size_t base = ((size_t)h * NCH + ch) * MLM + im;
#pragma unroll
    for (int ni = 0; ni < 4; ni++)
      pacc[base * HD_ + ni * 16 + m16] = acc_o[ni][r];
    if (m16 == 0){
      pml[base * 2]     = mreg[r];
      pml[base * 2 + 1] = lreg[r];
    }
  }
}

__global__ __launch_bounds__(64) void a3v_combine_kernel(
    const float* __restrict__ pacc, const float* __restrict__ pml,
    float* __restrict__ t1){
  const int im = blockIdx.x, h = blockIdx.y, lane = threadIdx.x;
  float M = -3.0e38f;
  for (int c = 0; c < NCH; c++)
    M = fmaxf(M, pml[(((size_t)h * NCH + c) * MLM + im) * 2]);
  float accv = 0.f, L = 0.f;
  for (int c = 0; c < NCH; c++){
    size_t base = ((size_t)h * NCH + c) * MLM + im;
    float mc = pml[base * 2], lc = pml[base * 2 + 1];
    float w = __expf(mc - M);
    accv += w * pacc[base * HD_ + lane];
    L += w * lc;
  }
  t1[((size_t)h * MLM + im) * HD_ + lane] = accv / L;
}

// ---------------- t2^T = (z @ t1)^T, bf16 [h][d][im] ----------------
__global__ __launch_bounds__(256) void zt1_kernel(
    const float* __restrict__ z, const float* __restrict__ t1,
    unsigned short* __restrict__ t2t){
  const int h = blockIdx.y;
  const int t = threadIdx.x;
  const int d = t & 63, ri = t >> 6;
  const int im = blockIdx.x * 4 + ri;
  const float* zr = z + ((size_t)h * MLM + im) * MLM;
  const float* t1h = t1 + (size_t)h * MLM * HD_;
  float acc = 0.f;
#pragma unroll 8
  for (int kk = 0; kk < MLM; kk++) acc += zr[kk] * t1h[(size_t)kk * HD_ + d];
  t2t[((size_t)h * HD_ + d) * MLM + im] = f2bf(acc);
}

// ---------------- out tile MFMA: 64 tokens x 1 head per block ----------------
__global__ __launch_bounds__(256) void out_tile_kernel(
    const unsigned short* __restrict__ q16, const unsigned short* __restrict__ klh,
    const unsigned short* __restrict__ t2t, const unsigned short* __restrict__ v16,
    const float* __restrict__ resw, unsigned short* __restrict__ outh){
  __shared__ __align__(16) unsigned short smem[64 * 72 * 2 + 64 * 264];
  unsigned short* qs16 = smem;                 // 64 x 72
  unsigned short* kb16 = smem + 64 * 72;       // 64 x 72 (kl chunks, t2t chunks)
  unsigned short* Ps   = smem + 64 * 72 * 2;   // 64 x 264 (P bf16; later O f32 + v tile)
  const int bid = blockIdx.x;
  const int h = bid & 7, tile = bid >> 3;
  const int n0 = PADR + tile * 64;
  const int t = threadIdx.x;
  const int lane = t & 63, w = t >> 6;
  const int m16 = lane & 15, quad = lane >> 4;

  {
    const unsigned short* qh = q16 + (size_t)h * NP_ * HD_;
    for (int idx = t; idx < 512; idx += 256){
      int row = idx >> 3, off = (idx & 7) * 8;
      int n = n0 + row;
      uint4 val = {0u, 0u, 0u, 0u};
      if (n < NP_) val = *(const uint4*)(qh + (size_t)n * HD_ + off);
      *(uint4*)(qs16 + row * 72 + off) = val;
    }
  }
  f32x4 z4 = {0.f, 0.f, 0.f, 0.f};
  f32x4 acc_s[16];
#pragma unroll
  for (int i = 0; i < 16; i++) acc_s[i] = z4;
  const unsigned short* klg = klh + (size_t)h * MLM * HD_;
  for (int m = 0; m < 4; m++){
    __syncthreads();
    for (int idx = t; idx < 512; idx += 256){
      int row = idx >> 3, off = (idx & 7) * 8;
      *(uint4*)(kb16 + row * 72 + off) =
          *(const uint4*)(klg + (size_t)(m * 64 + row) * HD_ + off);
    }
    __syncthreads();
#pragma unroll
    for (int kc = 0; kc < 64; kc += 32){
      bf16x8 a = *(const bf16x8*)(qs16 + (w * 16 + m16) * 72 + kc + quad * 8);
#pragma unroll
      for (int ni = 0; ni < 4; ni++){
        bf16x8 b = *(const bf16x8*)(kb16 + (ni * 16 + m16) * 72 + kc + quad * 8);
        acc_s[m * 4 + ni] = __builtin_amdgcn_mfma_f32_16x16x32_bf16(a, b, acc_s[m * 4 + ni], 0, 0, 0);
      }
    }
  }
  __syncthreads();
#pragma unroll
  for (int r = 0; r < 4; r++){
    float mx = acc_s[0][r];
#pragma unroll
    for (int mc = 1; mc < 16; mc++) mx = fmaxf(mx, acc_s[mc][r]);
#pragma unroll
    for (int o = 1; o < 16; o <<= 1) mx = fmaxf(mx, __shfl_xor(mx, o));
    float p[16]; float sum = 0.f;
#pragma unroll
    for (int mc = 0; mc < 16; mc++){ p[mc] = __expf(acc_s[mc][r] - mx); sum += p[mc]; }
#pragma unroll
    for (int o = 1; o < 16; o <<= 1) sum += __shfl_xor(sum, o);
    float inv = 1.f / sum;
    int prow = (w * 16 + quad * 4 + r) * 264;
#pragma unroll
    for (int mc = 0; mc < 16; mc++)
      Ps[prow + (mc >> 2) * 64 + (mc & 3) * 16 + m16] = f2bf(p[mc] * inv);
  }
  f32x4 acc_o[4] = {z4, z4, z4, z4};
  const unsigned short* t2g = t2t + (size_t)h * HD_ * MLM;
  for (int ch = 0; ch < 4; ch++){
    __syncthreads();
    {
      int row = t >> 2, c8 = (t & 3) * 16;
      const unsigned short* src = t2g + (size_t)row * MLM + ch * 64 + c8;
      *(uint4*)(kb16 + row * 72 + c8)     = *(const uint4*)src;
      *(uint4*)(kb16 + row * 72 + c8 + 8) = *(const uint4*)(src + 8);
    }
    __syncthreads();
#pragma unroll
    for (int kc = 0; kc < 64; kc += 32){
      bf16x8 a = *(const bf16x8*)(Ps + (w * 16 + m16) * 264 + ch * 64 + kc + quad * 8);
#pragma unroll
      for (int ni = 0; ni < 4; ni++){
        bf16x8 b = *(const bf16x8*)(kb16 + (ni * 16 + m16) * 72 + kc + quad * 8);
        acc_o[ni] = __builtin_amdgcn_mfma_f32_16x16x32_bf16(a, b, acc_o[ni], 0, 0, 0);
      }
    }
  }
  __syncthreads();
  float* Obuf = (float*)Ps;                          // 64 x 66 f32
  unsigned short* vtile = (unsigned short*)(Obuf + 64 * 66);  // 96 x 72 bf16
#pragma unroll
  for (int r = 0; r < 4; r++){
    int row = w * 16 + quad * 4 + r;
#pragma unroll
    for (int ni = 0; ni < 4; ni++)
      Obuf[row * 66 + ni * 16 + m16] = acc_o[ni][r];
  }
  {
    const unsigned short* vh = v16 + (size_t)h * NP_ * HD_;
    for (int idx = t; idx < 768; idx += 256){
      int row = idx >> 3, off = (idx & 7) * 8;
      int nn = n0 - 16 + row;
      uint4 val = {0u, 0u, 0u, 0u};
      if (nn < NP_) val = *(const uint4*)(vh + (size_t)nn * HD_ + off);
      *(uint4*)(vtile + row * 72 + off) = val;
    }
  }
  __syncthreads();
  float wreg[33];
  {
    const float* wr = resw + h * 33;
#pragma unroll
    for (int kk = 0; kk < 33; kk++) wreg[kk] = wr[kk];
  }
  const int ty = t >> 4, tx = t & 15;
#pragma unroll
  for (int i = 0; i < 4; i++){
    int lrow = ty * 4 + i;
    float c0v = 0.f, c1v = 0.f, c2v = 0.f, c3v = 0.f;
    for (int kk = 0; kk < 33; kk++){
      uint2 uv = *(const uint2*)(vtile + (lrow + kk) * 72 + tx * 4);
      float wv = wreg[kk];
      c0v += __uint_as_float(uv.x << 16) * wv;
      c1v += __uint_as_float(uv.x & 0xffff0000u) * wv;
      c2v += __uint_as_float(uv.y << 16) * wv;
      c3v += __uint_as_float(uv.y & 0xffff0000u) * wv;
    }
    int trow = tile * 64 + lrow;
    if (trow < NTOK){
      const float* orow = Obuf + lrow * 66 + tx * 4;
      unsigned long long pk =
          (unsigned long long)f2bf(orow[0] + c0v)
        | ((unsigned long long)f2bf(orow[1] + c1v) << 16)
        | ((unsigned long long)f2bf(orow[2] + c2v) << 32)
        | ((unsigned long long)f2bf(orow[3] + c3v) << 48);
      *(unsigned long long*)(outh + (size_t)trow * D_ + h * HD_ + tx * 4) = pk;
    }
  }
}

// ---------------- proj MFMA: h += outh @ out_wt^T + bias ----------------
// A rows beyond NTOK (up to 20864) read in-workspace garbage; their C rows
// are masked at store. B grid exact (512).
__global__ __launch_bounds__(256) void proj_mfma_kernel(
    const unsigned short* __restrict__ A, const unsigned short* __restrict__ Bt,
    const float* __restrict__ bias, float* __restrict__ h){
  __shared__ unsigned short As[128 * 64], Bs[128 * 64];
  f32x4 z4 = {0.f, 0.f, 0.f, 0.f};
  f32x4 acc[4][4];
#pragma unroll
  for (int i = 0; i < 4; i++)
#pragma unroll
    for (int j = 0; j < 4; j++) acc[i][j] = z4;
  const int bm = blockIdx.x * 128, bn = blockIdx.y * 128;
  mfma_tile128(A, bm, Bt, bn, D_, acc, As, Bs);
  const int lane = threadIdx.x & 63, wave = threadIdx.x >> 6;
  const int wr = wave >> 1, wc = wave & 1;
  const int m16 = lane & 15, quad = lane >> 4;
#pragma unroll
  for (int mi = 0; mi < 4; mi++)
#pragma unroll
    for (int ni = 0; ni < 4; ni++){
      int col = bn + wc * 64 + ni * 16 + m16;
      float bv = bias[col];
#pragma unroll
      for (int r = 0; r < 4; r++){
        int row = bm + wr * 64 + mi * 16 + quad * 4 + r;
        if (row < NTOK) h[(size_t)row * D_ + col] += acc[mi][ni][r] + bv;
      }
    }
}

// ---------------- PPEG ----------------
__global__ __launch_bounds__(512) void ppeg_combine_kernel(
    const float* __restrict__ w7, const float* __restrict__ b7,
    const float* __restrict__ w5, const float* __restrict__ b5,
    const float* __restrict__ w3, const float* __restrict__ b3,
    float* __restrict__ wcomb, float* __restrict__ bcomb){
  const int c = threadIdx.x;
#pragma unroll
  for (int i = 0; i < 7; i++){
#pragma unroll
    for (int j = 0; j < 7; j++){
      int di = i - 3, dj = j - 3;
      float wv = w7[(size_t)c * 49 + i * 7 + j];
      if (di >= -2 && di <= 2 && dj >= -2 && dj <= 2)
        wv += w5[(size_t)c * 25 + (di + 2) * 5 + (dj + 2)];
      if (di >= -1 && di <= 1 && dj >= -1 && dj <= 1)
        wv += w3[(size_t)c * 9 + (di + 1) * 3 + (dj + 1)];
      if (di == 0 && dj == 0) wv += 1.f;
      wcomb[(size_t)(i * 7 + j) * 512 + c] = wv;
    }
  }
  bcomb[c] = b7[c] + b5[c] + b3[c];
}

// y-banded XCD map: xcd = bid&7 owns rows [xcd*18, xcd*18+18)
__global__ __launch_bounds__(512) void ppeg_conv_kernel(
    const float* __restrict__ h, const float* __restrict__ wcomb,
    const float* __restrict__ bcomb, float* __restrict__ h2){
  const int c = threadIdx.x;
  const int bid = blockIdx.x;
  const int xcd = bid & 7;
  const int idx = bid >> 3;          // 0..323
  const int y = xcd * 18 + idx / 18;
  const int x0 = (idx % 18) * 8;
  float wc[49];
#pragma unroll
  for (int kk = 0; kk < 49; kk++) wc[kk] = wcomb[(size_t)kk * 512 + c];
  float acc[8];
  const float bv = bcomb[c];
#pragma unroll
  for (int p = 0; p < 8; p++) acc[p] = bv;
#pragma unroll
  for (int i = 0; i < 7; i++){
    const int yy = y + i - 3;
    if (yy < 0 || yy >= HHW) continue;
    const float* hrow = h + (size_t)(1 + yy * HHW) * D_ + c;
    float line[14];
#pragma unroll
    for (int j = 0; j < 14; j++){
      const int xx = x0 + j - 3;
      line[j] = (xx >= 0 && xx < HHW) ? hrow[(size_t)xx * D_] : 0.f;
    }
#pragma unroll
    for (int p = 0; p < 8; p++)
#pragma unroll
      for (int j = 0; j < 7; j++)
        acc[p] += line[p + j] * wc[i * 7 + j];
  }
#pragma unroll
  for (int p = 0; p < 8; p++)
    h2[(size_t)(1 + y * HHW + x0 + p) * D_ + c] = acc[p];
}

// ---------------- final ----------------
__global__ __launch_bounds__(512) void final_kernel(
    const float* __restrict__ h, const float* __restrict__ w,
    const float* __restrict__ b, const float* __restrict__ fc3w,
    const float* __restrict__ fc3b, float* __restrict__ out){
  __shared__ float vec[512];
  __shared__ float s8[8];
  __shared__ float lg[4];
  const int t = threadIdx.x;
  float x = h[t];
  float v = waveSumF(x);
  if ((t & 63) == 0) s8[t >> 6] = v;
  __syncthreads();
  float sum = 0.f;
#pragma unroll
  for (int i = 0; i < 8; i++) sum += s8[i];
  float mu = sum * (1.f / 512.f);
  __syncthreads();
  float d = x - mu;
  v = waveSumF(d * d);
  if ((t & 63) == 0) s8[t >> 6] = v;
  __syncthreads();
  float var = 0.f;
#pragma unroll
  for (int i = 0; i < 8; i++) var += s8[i];
  var *= (1.f / 512.f);
  float rs = rsqrtf(var + 1e-5f);
  vec[t] = d * rs * w[t] + b[t];
  __syncthreads();
  if (t < 4){
    float acc = fc3b[t];
    for (int kk = 0; kk < 512; kk++) acc += vec[kk] * fc3w[kk * 4 + t];
    lg[t] = acc;
  }
  __syncthreads();
  if (t == 0){
    float m = fmaxf(fmaxf(lg[0], lg[1]), fmaxf(lg[2], lg[3]));
    float e[4], se = 0.f;
#pragma unroll
    for (int i = 0; i < 4; i++){ e[i] = __expf(lg[i] - m); se += e[i]; }
    int am = 0; float bm = lg[0];
#pragma unroll
    for (int i = 1; i < 4; i++) if (lg[i] > bm){ bm = lg[i]; am = i; }
#pragma unroll
    for (int i = 0; i < 4; i++){ out[i] = lg[i]; out[4 + i] = e[i] / se; }
    out[8] = (float)am;
  }
}

// ---------------------------------------------------------------------------
extern "C" void kernel_launch(void* const* d_in, const int* in_sizes, int n_in,
                              void* d_out, int out_size, void* d_ws, size_t ws_size,
                              hipStream_t stream) {
  const float* x       = (const float*)d_in[0];
  const float* fc1_w   = (const float*)d_in[1];
  const float* fc1_b   = (const float*)d_in[2];
  const float* cls_tok = (const float*)d_in[3];
  const float* l1_nw   = (const float*)d_in[4];
  const float* l1_nb   = (const float*)d_in[5];
  const float* l1_qkvw = (const float*)d_in[6];
  const float* l1_outw = (const float*)d_in[7];
  const float* l1_outb = (const float*)d_in[8];
  const float* l1_resw = (const float*)d_in[9];
  const float* ppeg_w7 = (const float*)d_in[10];
  const float* ppeg_b7 = (const float*)d_in[11];
  const float* ppeg_w5 = (const float*)d_in[12];
  const float* ppeg_b5 = (const float*)d_in[13];
  const float* ppeg_w3 = (const float*)d_in[14];
  const float* ppeg_b3 = (const float*)d_in[15];
  const float* l2_nw   = (const float*)d_in[16];
  const float* l2_nb   = (const float*)d_in[17];
  const float* l2_qkvw = (const float*)d_in[18];
  const float* l2_outw = (const float*)d_in[19];
  const float* l2_outb = (const float*)d_in[20];
  const float* l2_resw = (const float*)d_in[21];
  const float* norm_w  = (const float*)d_in[22];
  const float* norm_b  = (const float*)d_in[23];
  const float* fc3_w   = (const float*)d_in[24];
  const float* fc3_b   = (const float*)d_in[25];

  // workspace layout (float units)
  float* W = (float*)d_ws;
  size_t o = 0;
  float* hbuf = W + o; o += (size_t)NTOK * D_;
  float* xp   = W + o; o += (size_t)NP_ * D_;   // xph / pacc+pml / outh
  float* qb   = W + o; o += (size_t)NH_ * NP_ * HD_;   // bf16 q; also Ah pre-layer
  float* kb   = W + o; o += (size_t)NH_ * NP_ * HD_;   // bf16 k
  float* vb   = W + o; o += (size_t)NH_ * NP_ * HD_;   // bf16 v
  float* qlb  = W + o; o += (size_t)NH_ * MLM * HD_;
  float* klb  = W + o; o += (size_t)NH_ * MLM * HD_;
  float* a2b  = W + o; o += (size_t)NH_ * MLM * MLM;
  float* zfin = W + o; o += (size_t)NH_ * MLM * MLM;   // final z fp32 (zt1 input)
  float* t1b  = W + o; o += (size_t)NH_ * MLM * HD_;
  float* t2r  = W + o; o += (size_t)NH_ * MLM * HD_;   // t2t bf16 lives here
  float* scalf = W + o; o += 16;
  float* wcomb = W + o; o += 49 * 512;
  float* bcomb = W + o; o += 512;
  unsigned short* fc1_wt  = (unsigned short*)(W + o); o += (size_t)D_ * E_ / 2;
  unsigned short* qkv_wt1 = (unsigned short*)(W + o); o += (size_t)1536 * D_ / 2;
  unsigned short* qkv_wt2 = (unsigned short*)(W + o); o += (size_t)1536 * D_ / 2;
  unsigned short* out_wt1 = (unsigned short*)(W + o); o += (size_t)D_ * D_ / 2;
  unsigned short* out_wt2 = (unsigned short*)(W + o); o += (size_t)D_ * D_ / 2;
  unsigned short* qlh = (unsigned short*)(W + o); o += (size_t)NH_ * MLM * HD_ / 2;
  unsigned short* klh = (unsigned short*)(W + o); o += (size_t)NH_ * MLM * HD_ / 2;
  // pinv split-bf16 arrays: 18 x [NH][256][256] ushorts
  const size_t HM = (size_t)NH_ * MLM * MLM;
  unsigned short* usp = (unsigned short*)(W + o); o += 18 * HM / 2;
  unsigned short* a2sh  = usp; usp += HM;
  unsigned short* a2sl  = usp; usp += HM;
  unsigned short* tah_s = usp; usp += HM;
  unsigned short* tal_s = usp; usp += HM;
  unsigned short* tath_s = usp; usp += HM;
  unsigned short* tatl_s = usp; usp += HM;
  unsigned short* tbth_s = usp; usp += HM;
  unsigned short* tbtl_s = usp; usp += HM;
  unsigned short* tcth_s = usp; usp += HM;
  unsigned short* tctl_s = usp; usp += HM;
  unsigned short* zsh[2], *zsl[2], *zsth[2], *zstl[2];
  for (int s = 0; s < 2; s++){
    zsh[s]  = usp; usp += HM;
    zsl[s]  = usp; usp += HM;
    zsth[s] = usp; usp += HM;
    zstl[s] = usp; usp += HM;
  }
  float* hbuf2 = W + o; o += (size_t)NTOK * D_;       // ppeg ping-pong target

  unsigned short* xph = (unsigned short*)xp;
  float* pacc = xp;
  float* pml  = xp + (size_t)NH_ * NCH * MLM * HD_;
  unsigned short* outh = (unsigned short*)xp;
  unsigned short* Ah  = (unsigned short*)qb;
  unsigned short* q16 = (unsigned short*)qb;
  unsigned short* k16 = (unsigned short*)kb;
  unsigned short* v16 = (unsigned short*)vb;
  unsigned short* t2t = (unsigned short*)t2r;

  // ---- weight prep (once per launch) ----
  wtrans_kernel<<<dim3(E_ / 32, D_ / 32), dim3(32, 8), 0, stream>>>(fc1_w, fc1_wt, E_, D_);
  wtrans_kernel<<<dim3(D_ / 32, 1536 / 32), dim3(32, 8), 0, stream>>>(l1_qkvw, qkv_wt1, D_, 1536);
  wtrans_kernel<<<dim3(D_ / 32, 1536 / 32), dim3(32, 8), 0, stream>>>(l2_qkvw, qkv_wt2, D_, 1536);
  wtrans_kernel<<<dim3(D_ / 32, D_ / 32), dim3(32, 8), 0, stream>>>(l1_outw, out_wt1, D_, D_);
  wtrans_kernel<<<dim3(D_ / 32, D_ / 32), dim3(32, 8), 0, stream>>>(l2_outw, out_wt2, D_, D_);
  ppeg_combine_kernel<<<1, 512, 0, stream>>>(ppeg_w7, ppeg_b7, ppeg_w5, ppeg_b5,
                                             ppeg_w3, ppeg_b3, wcomb, bcomb);

  // ---- fc1 (maxpool -> bf16 -> MFMA 128-tile) ----
  pool_bf16_kernel<<<20480, 256, 0, stream>>>(x, Ah);
  fc1_mfma_kernel<<<dim3(160, 4), 256, 0, stream>>>(Ah, fc1_wt, fc1_b, hbuf);
  cls_kernel<<<2, 256, 0, stream>>>(cls_tok, hbuf);

  auto run_layer = [&](float* hcur, const float* nw, const float* nb,
                       const unsigned short* qkvwt, const unsigned short* outwt,
                       const float* outb, const float* resw){
    ln_pad_kernel<<<NP_ / 4, 256, 0, stream>>>(hcur, nw, nb, xph);
    qkv_mfma_kernel<<<dim3(164, 12), 256, 0, stream>>>(xph, qkvwt, q16, k16, v16);
    landmark_kernel<<<dim3(64, 8), 256, 0, stream>>>(q16, k16, qlb, klb, qlh, klh);
    a2_kernel<<<dim3(256, 8), 256, 0, stream>>>(qlb, klb, a2b, a2sh, a2sl);
    pinv_scale_kernel<<<8, 256, 0, stream>>>(a2b, scalf);
    pinv_init_kernel<<<dim3(256, 8), 256, 0, stream>>>(a2b, scalf,
        zsh[0], zsl[0], zsth[0], zstl[0]);
    int c = 0;
    for (int it = 0; it < 6; it++){
      // ta = a2 @ z                  (RM for A-use; -ta^T for B-use)
      bmm256_split_kernel<<<512, 256, 0, stream>>>(
          a2sh, a2sl, zsth[c], zstl[c], 0.f, 1.f,
          tah_s, tal_s, tath_s, tatl_s, nullptr, 0x8000u);
      // tb = ta @ (7I - ta)          (-tb^T only)
      bmm256_split_kernel<<<512, 256, 0, stream>>>(
          tah_s, tal_s, tath_s, tatl_s, 7.f, 1.f,
          nullptr, nullptr, tbth_s, tbtl_s, nullptr, 0x8000u);
      // tc = ta @ (15I - tb)         (-tc^T only)
      bmm256_split_kernel<<<512, 256, 0, stream>>>(
          tah_s, tal_s, tbth_s, tbtl_s, 15.f, 1.f,
          nullptr, nullptr, tcth_s, tctl_s, nullptr, 0x8000u);
      // z' = 0.25 * z @ (13I - tc)   (RM + +z'^T; fp32 on last iter)
      bmm256_split_kernel<<<512, 256, 0, stream>>>(
          zsh[c], zsl[c], tcth_s, tctl_s, 13.f, 0.25f,
          zsh[c ^ 1], zsl[c ^ 1], zsth[c ^ 1], zstl[c ^ 1],
          (it == 5) ? zfin : nullptr, 0u);
      c ^= 1;
    }
    a3v_part_kernel<<<NCH * 32, 256, 0, stream>>>(qlh, k16, v16, pacc, pml);
    a3v_combine_kernel<<<dim3(256, 8), 64, 0, stream>>>(pacc, pml, t1b);
    zt1_kernel<<<dim3(64, 8), 256, 0, stream>>>(zfin, t1b, t2t);
    out_tile_kernel<<<325 * 8, 256, 0, stream>>>(q16, klh, t2t, v16, resw, outh);
    proj_mfma_kernel<<<dim3(163, 4), 256, 0, stream>>>(outh, outwt, outb, hcur);
  };

  run_layer(hbuf, l1_nw, l1_nb, qkv_wt1, out_wt1, l1_outb, l1_resw);
  // PPEG: conv writes rows 1.. of hbuf2 directly; cls row copied
  ppeg_conv_kernel<<<2592, 512, 0, stream>>>(hbuf, wcomb, bcomb, hbuf2);
  row0_copy_kernel<<<2, 256, 0, stream>>>(hbuf, hbuf2);
  run_layer(hbuf2, l2_nw, l2_nb, qkv_wt2, out_wt2, l2_outb, l2_resw);
  final_kernel<<<1, 512, 0, stream>>>(hbuf2, norm_w, norm_b, fc3_w, fc3_b, (float*)d_out);
}

// Round 16
// 1418.211 us; speedup vs baseline: 1.0277x; 1.0139x over previous
//
#include <hip/hip_runtime.h>

// ---------------------------------------------------------------------------
// TransMIL forward on MI355X.
//   r0: 12995 baseline -> r12: 1444 (bmm 32x32/512-blk/XCD + ln_pad vec).
//   r13: 1423 — BEST (ln_pad wave-per-row, a3v/out_tile/ppeg XCD pinning,
//        landmark 256-thr). Session: 1699.6 -> 1422.7 us (-16.3%).
//   r14: 1452 REG (qkv LDS-retile: 4M bank conflicts, counter-evidenced).
//   r15: 1442 REG (bmm 16x16/1-wave: no staging/MFMA overlap).
//   r16: 1457 REG (gload_lds linear LDS: 16-way read conflicts).
//   r17: 1438 REG (swizzle fixed conflicts, -19 vs r16, still +15 vs r13:
//        gload_lds barrier-drain costs more than reg-staging here — these
//        GEMMs are latency/occupancy-bound, not staging-VALU-bound).
//   r18: REVERT to r13 verbatim per pre-committed falsifier. GEMM staging
//        path closed; r13 is the verified optimum of this decomposition.
//        (resubmitted verbatim — round 15 was an infra timeout.)
// ---------------------------------------------------------------------------

constexpr int D_    = 512;
constexpr int E_    = 1024;
constexpr int NTOK  = 20737;
constexpr int NP_   = 20992;   // padded seq len (255 zero rows at FRONT)
constexpr int NH_   = 8;
constexpr int HD_   = 64;
constexpr int MLM   = 256;     // landmarks
constexpr int LCH   = 82;      // tokens per landmark
constexpr int HHW   = 144;
constexpr int NFEAT = 20736;   // 144*144
constexpr int PADR  = 255;
constexpr int NCH   = 41;      // a3v N-chunks
constexpr int CHTOK = 512;     // tokens per chunk (8 subchunks of 64)

typedef __attribute__((ext_vector_type(8))) short bf16x8;
typedef __attribute__((ext_vector_type(4))) float f32x4;

__device__ __forceinline__ unsigned short f2bf(float f){
  unsigned int u = __float_as_uint(f);
  unsigned int r = u + 0x7fffu + ((u >> 16) & 1u);
  return (unsigned short)(r >> 16);
}
__device__ __forceinline__ float bfu(unsigned short u){
  return __uint_as_float((unsigned int)u << 16);
}

// ---------------- reduction helpers ----------------
__device__ __forceinline__ float waveMaxF(float v){
#pragma unroll
  for (int o = 32; o > 0; o >>= 1) v = fmaxf(v, __shfl_xor(v, o));
  return v;
}
__device__ __forceinline__ float waveSumF(float v){
#pragma unroll
  for (int o = 32; o > 0; o >>= 1) v += __shfl_xor(v, o);
  return v;
}
__device__ __forceinline__ float blockMax256(float v, float* sbuf){
  v = waveMaxF(v);
  if ((threadIdx.x & 63) == 0) sbuf[threadIdx.x >> 6] = v;
  __syncthreads();
  float r = fmaxf(fmaxf(sbuf[0], sbuf[1]), fmaxf(sbuf[2], sbuf[3]));
  __syncthreads();
  return r;
}
__device__ __forceinline__ float blockSum256(float v, float* sbuf){
  v = waveSumF(v);
  if ((threadIdx.x & 63) == 0) sbuf[threadIdx.x >> 6] = v;
  __syncthreads();
  float r = sbuf[0] + sbuf[1] + sbuf[2] + sbuf[3];
  __syncthreads();
  return r;
}

// ---------------- weight prep: W[K][N] fp32 -> Wt[N][K] bf16 ----------------
__global__ __launch_bounds__(256) void wtrans_kernel(
    const float* __restrict__ W, unsigned short* __restrict__ Wt, int K, int N){
  __shared__ float tile[32][33];
  const int kb = blockIdx.x * 32, nb = blockIdx.y * 32;
  const int tx = threadIdx.x, ty = threadIdx.y;
  for (int i = ty; i < 32; i += 8) tile[i][tx] = W[(size_t)(kb + i) * N + nb + tx];
  __syncthreads();
  for (int i = ty; i < 32; i += 8)
    Wt[(size_t)(nb + i) * K + kb + tx] = f2bf(tile[tx][i]);
}

// ---------------- maxpool2 + bf16 ----------------
__global__ __launch_bounds__(256) void pool_bf16_kernel(
    const float* __restrict__ x, unsigned short* __restrict__ Ah){
  size_t idx4 = ((size_t)blockIdx.x * 256 + threadIdx.x) * 4;
  size_t m = idx4 >> 10, e = idx4 & 1023;
  float4 a = *(const float4*)(x + (m * 2) * E_ + e);
  float4 b = *(const float4*)(x + (m * 2 + 1) * E_ + e);
  unsigned long long pk =
      (unsigned long long)f2bf(fmaxf(a.x, b.x))
    | ((unsigned long long)f2bf(fmaxf(a.y, b.y)) << 16)
    | ((unsigned long long)f2bf(fmaxf(a.z, b.z)) << 32)
    | ((unsigned long long)f2bf(fmaxf(a.w, b.w)) << 48);
  *(unsigned long long*)(Ah + idx4) = pk;
}

// ---------------- MFMA 128x128 tile core, BK=64 (bf16 in, fp32 acc) ----------
__device__ __forceinline__ void mfma_tile128(
    const unsigned short* __restrict__ A, int arows, int bm,
    const unsigned short* __restrict__ Bt, int bn, int K,
    f32x4 acc[4][4], unsigned short* As, unsigned short* Bs){
  const int t = threadIdx.x;
  const int lane = t & 63, wave = t >> 6;
  const int wr = wave >> 1, wc = wave & 1;
  const int m16 = lane & 15, quad = lane >> 4;
  for (int kc = 0; kc < K; kc += 64){
    for (int idx = t; idx < 1024; idx += 256){
      int row = idx >> 3, off = (idx & 7) * 8;
      int ga = bm + row;
      ulonglong2 av = {0ull, 0ull};
      if (ga < arows) av = *(const ulonglong2*)(A + (size_t)ga * K + kc + off);
      *(ulonglong2*)(As + row * 72 + off) = av;
      ulonglong2 bv = *(const ulonglong2*)(Bt + (size_t)(bn + row) * K + kc + off);
      *(ulonglong2*)(Bs + row * 72 + off) = bv;
    }
    __syncthreads();
#pragma unroll
    for (int k2 = 0; k2 < 64; k2 += 32){
      bf16x8 af[4], bf[4];
#pragma unroll
      for (int mi = 0; mi < 4; mi++)
        af[mi] = *(const bf16x8*)(As + (wr * 64 + mi * 16 + m16) * 72 + k2 + quad * 8);
#pragma unroll
      for (int ni = 0; ni < 4; ni++)
        bf[ni] = *(const bf16x8*)(Bs + (wc * 64 + ni * 16 + m16) * 72 + k2 + quad * 8);
#pragma unroll
      for (int mi = 0; mi < 4; mi++)
#pragma unroll
        for (int ni = 0; ni < 4; ni++)
          acc[mi][ni] = __builtin_amdgcn_mfma_f32_16x16x32_bf16(af[mi], bf[ni], acc[mi][ni], 0, 0, 0);
    }
    __syncthreads();
  }
}

// ---------------- fc1 ----------------
__global__ __launch_bounds__(256) void fc1_mfma_kernel(
    const unsigned short* __restrict__ Ah, const unsigned short* __restrict__ Bt,
    const float* __restrict__ bias, float* __restrict__ h){
  __shared__ unsigned short As[128 * 72], Bs[128 * 72];
  f32x4 z4 = {0.f, 0.f, 0.f, 0.f};
  f32x4 acc[4][4];
#pragma unroll
  for (int i = 0; i < 4; i++)
#pragma unroll
    for (int j = 0; j < 4; j++) acc[i][j] = z4;
  const int bm = blockIdx.x * 128, bn = blockIdx.y * 128;
  mfma_tile128(Ah, 20480, bm, Bt, bn, E_, acc, As, Bs);
  const int lane = threadIdx.x & 63, wave = threadIdx.x >> 6;
  const int wr = wave >> 1, wc = wave & 1;
  const int m16 = lane & 15, quad = lane >> 4;
#pragma unroll
  for (int mi = 0; mi < 4; mi++)
#pragma unroll
    for (int ni = 0; ni < 4; ni++){
      int col = bn + wc * 64 + ni * 16 + m16;
      float bv = bias[col];
#pragma unroll
      for (int r = 0; r < 4; r++){
        int row = bm + wr * 64 + mi * 16 + quad * 4 + r;
        float vv = fmaxf(acc[mi][ni][r] + bv, 0.f);
        h[(size_t)(1 + row) * D_ + col] = vv;
        if (row < 256) h[(size_t)(20481 + row) * D_ + col] = vv;
      }
    }
}

__global__ void cls_kernel(const float* __restrict__ cls, float* __restrict__ h){
  int c = blockIdx.x * 256 + threadIdx.x;
  if (c < D_) h[c] = cls[c];
}

__global__ void row0_copy_kernel(const float* __restrict__ src, float* __restrict__ dst){
  int c = blockIdx.x * 256 + threadIdx.x;
  if (c < D_) dst[c] = src[c];
}

// ---------------- layernorm -> zero-padded bf16 xph (wave-per-row) ----------
__global__ __launch_bounds__(256) void ln_pad_kernel(
    const float* __restrict__ h, const float* __restrict__ w,
    const float* __restrict__ b, unsigned short* __restrict__ xph){
  const int wv = threadIdx.x >> 6, lane = threadIdx.x & 63;
  const int r = blockIdx.x * 4 + wv;
  unsigned int* xp32 = (unsigned int*)xph;
  if (r < PADR){
    uint4 z = {0u, 0u, 0u, 0u};
    *(uint4*)(xp32 + (size_t)r * 256 + lane * 4) = z;
    return;
  }
  const float* x = h + (size_t)(r - PADR) * D_;
  float4 a0 = *(const float4*)(x + lane * 8);
  float4 a1 = *(const float4*)(x + lane * 8 + 4);
  float s = (a0.x + a0.y) + (a0.z + a0.w) + (a1.x + a1.y) + (a1.z + a1.w);
  float mu = waveSumF(s) * (1.f / 512.f);
  float d[8] = {a0.x - mu, a0.y - mu, a0.z - mu, a0.w - mu,
                a1.x - mu, a1.y - mu, a1.z - mu, a1.w - mu};
  float vs = 0.f;
#pragma unroll
  for (int i = 0; i < 8; i++) vs += d[i] * d[i];
  float var = waveSumF(vs) * (1.f / 512.f);
  float rs = rsqrtf(var + 1e-5f);
  float4 w0 = *(const float4*)(w + lane * 8);
  float4 w1 = *(const float4*)(w + lane * 8 + 4);
  float4 b0 = *(const float4*)(b + lane * 8);
  float4 b1 = *(const float4*)(b + lane * 8 + 4);
  float wv8[8] = {w0.x, w0.y, w0.z, w0.w, w1.x, w1.y, w1.z, w1.w};
  float bv8[8] = {b0.x, b0.y, b0.z, b0.w, b1.x, b1.y, b1.z, b1.w};
  uint4 pk;
  unsigned int* pkp = (unsigned int*)&pk;
#pragma unroll
  for (int i = 0; i < 4; i++){
    unsigned int lo = f2bf(d[2 * i] * rs * wv8[2 * i] + bv8[2 * i]);
    unsigned int hi = f2bf(d[2 * i + 1] * rs * wv8[2 * i + 1] + bv8[2 * i + 1]);
    pkp[i] = lo | (hi << 16);
  }
  *(uint4*)(xp32 + (size_t)r * 256 + lane * 4) = pk;
}

// ---------------- qkv MFMA ----------------
__global__ __launch_bounds__(256) void qkv_mfma_kernel(
    const unsigned short* __restrict__ A, const unsigned short* __restrict__ Bt,
    unsigned short* __restrict__ q16, unsigned short* __restrict__ k16,
    unsigned short* __restrict__ v16){
  __shared__ unsigned short As[128 * 72], Bs[128 * 72];
  f32x4 z4 = {0.f, 0.f, 0.f, 0.f};
  f32x4 acc[4][4];
#pragma unroll
  for (int i = 0; i < 4; i++)
#pragma unroll
    for (int j = 0; j < 4; j++) acc[i][j] = z4;
  const int bm = blockIdx.x * 128, bn = blockIdx.y * 128;
  mfma_tile128(A, NP_, bm, Bt, bn, D_, acc, As, Bs);
  const int lane = threadIdx.x & 63, wave = threadIdx.x >> 6;
  const int wr = wave >> 1, wc = wave & 1;
  const int m16 = lane & 15, quad = lane >> 4;
#pragma unroll
  for (int mi = 0; mi < 4; mi++)
#pragma unroll
    for (int ni = 0; ni < 4; ni++){
      int col = bn + wc * 64 + ni * 16 + m16;
      int which = col >> 9, hh = (col >> 6) & 7, d = col & 63;
      size_t cbase = (size_t)hh * NP_ * HD_ + d;
      unsigned short* dst;
      float sc = 1.f;
      if (which == 0){ dst = q16; sc = 0.125f; }
      else if (which == 1) dst = k16;
      else dst = v16;
#pragma unroll
      for (int r = 0; r < 4; r++){
        int row = bm + wr * 64 + mi * 16 + quad * 4 + r;
        dst[cbase + (size_t)row * HD_] = f2bf(acc[mi][ni][r] * sc);
      }
    }
}

// ---------------- landmarks (wave-per-landmark, 4 per block) ----------------
__global__ __launch_bounds__(256) void landmark_kernel(
    const unsigned short* __restrict__ q16, const unsigned short* __restrict__ k16,
    float* __restrict__ ql, float* __restrict__ kl,
    unsigned short* __restrict__ qlh, unsigned short* __restrict__ klh){
  const int wv = threadIdx.x >> 6, d = threadIdx.x & 63;
  const int im = blockIdx.x * 4 + wv, h = blockIdx.y;
  size_t base = ((size_t)h * NP_ + (size_t)im * LCH) * HD_ + d;
  float sq = 0.f, sk = 0.f;
  for (int r = 0; r < LCH; r++){
    sq += bfu(q16[base + (size_t)r * HD_]);
    sk += bfu(k16[base + (size_t)r * HD_]);
  }
  float qm = sq * (1.f / 82.f), km = sk * (1.f / 82.f);
  size_t oidx = ((size_t)h * MLM + im) * HD_ + d;
  ql[oidx] = qm;  qlh[oidx] = f2bf(qm);
  kl[oidx] = km;  klh[oidx] = f2bf(km);
}

// ---------------- a2 = softmax(ql @ kl^T); also split-bf16 materialized ------
__global__ __launch_bounds__(256) void a2_kernel(
    const float* __restrict__ ql, const float* __restrict__ kl,
    float* __restrict__ a2, unsigned short* __restrict__ a2h,
    unsigned short* __restrict__ a2l){
  const int im = blockIdx.x, h = blockIdx.y, t = threadIdx.x;
  __shared__ __align__(16) float qs[64];
  __shared__ float s4[4];
  if (t < 64) qs[t] = ql[((size_t)h * MLM + im) * HD_ + t];
  __syncthreads();
  const float4* kr4 = (const float4*)(kl + ((size_t)h * MLM + t) * HD_);
  const float4* qs4 = (const float4*)qs;
  float s = 0.f;
#pragma unroll
  for (int d4 = 0; d4 < 16; d4++){
    float4 kv = kr4[d4], qv = qs4[d4];
    s += qv.x*kv.x + qv.y*kv.y + qv.z*kv.z + qv.w*kv.w;
  }
  float mx = blockMax256(s, s4);
  float e = __expf(s - mx);
  float S = blockSum256(e, s4);
  float v = e / S;
  size_t idx = ((size_t)h * MLM + im) * MLM + t;
  a2[idx] = v;
  unsigned short hi = f2bf(v);
  a2h[idx] = hi;
  a2l[idx] = f2bf(v - bfu(hi));
}

// ---------------- pinv scale: col-sum max only (rows of softmax sum to 1) ----
__global__ __launch_bounds__(256) void pinv_scale_kernel(
    const float* __restrict__ a2, float* __restrict__ scal){
  const int h = blockIdx.x, j = threadIdx.x;
  const float* A = a2 + (size_t)h * MLM * MLM;
  float cs = 0.f;
  for (int t = 0; t < MLM; t++) cs += A[(size_t)t * MLM + j];
  __shared__ float s4[4];
  float cmax = blockMax256(cs, s4);
  if (j == 0) scal[h] = cmax;
}

// z0 = a2^T * inv, materialized as split-bf16 row-major AND transposed
__global__ __launch_bounds__(256) void pinv_init_kernel(
    const float* __restrict__ a2, const float* __restrict__ scal,
    unsigned short* __restrict__ zh, unsigned short* __restrict__ zl,
    unsigned short* __restrict__ zth, unsigned short* __restrict__ ztl){
  const int i = blockIdx.x, h = blockIdx.y, j = threadIdx.x;
  float cmax = scal[0];
#pragma unroll
  for (int hh = 1; hh < 8; hh++) cmax = fmaxf(cmax, scal[hh]);
  float inv = 1.f / cmax;          // rmax == 1 exactly (softmax rows)
  size_t idx = ((size_t)h * MLM + i) * MLM + j;
  float vr = a2[((size_t)h * MLM + j) * MLM + i] * inv;  // z0[i][j]
  float vt = a2[idx] * inv;                              // z0T[i][j] = z0[j][i]
  unsigned short hi = f2bf(vr);
  zh[idx] = hi; zl[idx] = f2bf(vr - bfu(hi));
  hi = f2bf(vt);
  zth[idx] = hi; ztl[idx] = f2bf(vt - bfu(hi));
}

// ---------------- batched 256^3 split-bf16 MFMA on pre-split operands --------
// 32x32 tiles, 1D grid of 512 blocks, head = bid&7 => all blocks of a head on
// one XCD (round-robin bid->XCD): stage k's writes are stage k+1's L2 hits.
__global__ __launch_bounds__(256) void bmm256_split_kernel(
    const unsigned short* __restrict__ Ahg, const unsigned short* __restrict__ Alg,
    const unsigned short* __restrict__ Bthg, const unsigned short* __restrict__ Btlg,
    float c0, float c1,
    unsigned short* __restrict__ Crh, unsigned short* __restrict__ Crl,
    unsigned short* __restrict__ Cth, unsigned short* __restrict__ Ctl,
    float* __restrict__ Cf, unsigned int tsgn){
  __shared__ __align__(16) unsigned short Ash[32 * 72], Asl[32 * 72];
  __shared__ __align__(16) unsigned short Bsh[32 * 72], Bsl[32 * 72];
  const int bid = blockIdx.x;
  const int h = bid & 7;               // XCD affinity
  const int tid2 = bid >> 3;           // 0..63
  const int bm = (tid2 & 7) * 32;
  const int bn = (tid2 >> 3) * 32;
  const int t = threadIdx.x, lane = t & 63, w = t >> 6;
  const int wr = w >> 1, wc = w & 1, m16 = lane & 15, quad = lane >> 4;
  const size_t hb = (size_t)h * 65536;
  const unsigned short* gAh0 = Ahg + hb + (size_t)bm * 256;
  const unsigned short* gAl0 = Alg + hb + (size_t)bm * 256;
  const unsigned short* gBh0 = Bthg + hb + (size_t)bn * 256;
  const unsigned short* gBl0 = Btlg + hb + (size_t)bn * 256;
  const int srow = t >> 3, soff = (t & 7) * 8;       // staging: 32 rows x 64 k
  const int sl = srow * 72 + soff;
  f32x4 acc = {0.f, 0.f, 0.f, 0.f};
  for (int kc = 0; kc < 256; kc += 64){
    {
      size_t g = (size_t)srow * 256 + kc + soff;
      *(uint4*)(Ash + sl) = *(const uint4*)(gAh0 + g);
      *(uint4*)(Asl + sl) = *(const uint4*)(gAl0 + g);
      *(uint4*)(Bsh + sl) = *(const uint4*)(gBh0 + g);
      *(uint4*)(Bsl + sl) = *(const uint4*)(gBl0 + g);
    }
    __syncthreads();
    if (c0 != 0.f && (bn & ~63) == kc){
      // diagonal patch: B_eff diag = c0 + stored; resplit (32 elems, in-window)
      if (t < 32){
        int kloc = bn - kc + t;        // n = bn+t, k = n, local k index
        float v = c0 + bfu(Bsh[t * 72 + kloc]) + bfu(Bsl[t * 72 + kloc]);
        unsigned short hi = f2bf(v);
        Bsh[t * 72 + kloc] = hi;
        Bsl[t * 72 + kloc] = f2bf(v - bfu(hi));
      }
      __syncthreads();
    }
#pragma unroll
    for (int k2 = 0; k2 < 64; k2 += 32){
      bf16x8 ah = *(const bf16x8*)(Ash + (wr * 16 + m16) * 72 + k2 + quad * 8);
      bf16x8 al = *(const bf16x8*)(Asl + (wr * 16 + m16) * 72 + k2 + quad * 8);
      bf16x8 bh = *(const bf16x8*)(Bsh + (wc * 16 + m16) * 72 + k2 + quad * 8);
      bf16x8 bl = *(const bf16x8*)(Bsl + (wc * 16 + m16) * 72 + k2 + quad * 8);
      acc = __builtin_amdgcn_mfma_f32_16x16x32_bf16(ah, bh, acc, 0, 0, 0);
      acc = __builtin_amdgcn_mfma_f32_16x16x32_bf16(ah, bl, acc, 0, 0, 0);
      acc = __builtin_amdgcn_mfma_f32_16x16x32_bf16(al, bh, acc, 0, 0, 0);
    }
    __syncthreads();
  }
#pragma unroll
  for (int r = 0; r < 4; r++){
    int row = bm + wr * 16 + quad * 4 + r;
    int col = bn + wc * 16 + m16;
    float v = c1 * acc[r];
    unsigned short hi = f2bf(v);
    unsigned short lo = f2bf(v - bfu(hi));
    size_t rm = hb + (size_t)row * 256 + col;
    if (Crh){ Crh[rm] = hi; Crl[rm] = lo; }
    if (Cth){
      size_t tm = hb + (size_t)col * 256 + row;
      Cth[tm] = hi ^ (unsigned short)tsgn;
      Ctl[tm] = lo ^ (unsigned short)tsgn;
    }
    if (Cf) Cf[rm] = v;
  }
}

// ---------------- a3v split-K flash, bf16 MFMA (XCD-pinned 1D grid) ---------
__global__ __launch_bounds__(256) void a3v_part_kernel(
    const unsigned short* __restrict__ qlh, const unsigned short* __restrict__ k16,
    const unsigned short* __restrict__ v16, float* __restrict__ pacc,
    float* __restrict__ pml){
  __shared__ __align__(16) unsigned short qs16[64 * 72];
  __shared__ __align__(16) unsigned short kb16[64 * 72];   // K, then P
  __shared__ __align__(16) unsigned short vt16[64 * 72];   // V^T [d][n]
  const int bid = blockIdx.x;
  const int h = bid & 7;
  const int j = bid >> 3;
  const int lt = j & 3;
  const int ch = j >> 2;
  const int t = threadIdx.x;
  const int lane = t & 63, w = t >> 6;
  const int m16 = lane & 15, quad = lane >> 4;

  const unsigned short* qg = qlh + ((size_t)h * MLM + lt * 64) * HD_;
  for (int idx = t; idx < 512; idx += 256){
    int row = idx >> 3, off = (idx & 7) * 8;
    *(uint4*)(qs16 + row * 72 + off) = *(const uint4*)(qg + (size_t)row * HD_ + off);
  }
  f32x4 z4 = {0.f, 0.f, 0.f, 0.f};
  f32x4 acc_o[4] = {z4, z4, z4, z4};
  float mreg[4], lreg[4];
#pragma unroll
  for (int r = 0; r < 4; r++){ mreg[r] = -3.0e38f; lreg[r] = 0.f; }
  const unsigned short* kg = k16 + ((size_t)h * NP_ + ch * CHTOK) * HD_;
  const unsigned short* vg = v16 + ((size_t)h * NP_ + ch * CHTOK) * HD_;

  for (int sc = 0; sc < 8; sc++){
    __syncthreads();
    for (int idx = t; idx < 512; idx += 256){
      int row = idx >> 3, off = (idx & 7) * 8;
      *(uint4*)(kb16 + row * 72 + off) =
          *(const uint4*)(kg + (size_t)(sc * 64 + row) * HD_ + off);
      uint4 pv = *(const uint4*)(vg + (size_t)(sc * 64 + row) * HD_ + off);
      unsigned int uu[4] = {pv.x, pv.y, pv.z, pv.w};
#pragma unroll
      for (int jj = 0; jj < 4; jj++){
        vt16[(off + 2 * jj)     * 72 + row] = (unsigned short)(uu[jj] & 0xffffu);
        vt16[(off + 2 * jj + 1) * 72 + row] = (unsigned short)(uu[jj] >> 16);
      }
    }
    __syncthreads();
    f32x4 acc_s[4] = {z4, z4, z4, z4};
#pragma unroll
    for (int kc = 0; kc < 64; kc += 32){
      bf16x8 a = *(const bf16x8*)(qs16 + (w * 16 + m16) * 72 + kc + quad * 8);
#pragma unroll
      for (int ni = 0; ni < 4; ni++){
        bf16x8 b = *(const bf16x8*)(kb16 + (ni * 16 + m16) * 72 + kc + quad * 8);
        acc_s[ni] = __builtin_amdgcn_mfma_f32_16x16x32_bf16(a, b, acc_s[ni], 0, 0, 0);
      }
    }
    __syncthreads();
#pragma unroll
    for (int r = 0; r < 4; r++){
      float cm = fmaxf(fmaxf(acc_s[0][r], acc_s[1][r]), fmaxf(acc_s[2][r], acc_s[3][r]));
#pragma unroll
      for (int o = 1; o < 16; o <<= 1) cm = fmaxf(cm, __shfl_xor(cm, o));
      // exact defer-max: skipping the rescale when no row grew is mult-by-1.0
      if (__any(cm > mreg[r])){
        float mn = fmaxf(mreg[r], cm);
        float scl = __expf(mreg[r] - mn);
        lreg[r] *= scl;
        acc_o[0][r] *= scl; acc_o[1][r] *= scl;
        acc_o[2][r] *= scl; acc_o[3][r] *= scl;
        mreg[r] = mn;
      }
      float mcur = mreg[r];
      float p0 = __expf(acc_s[0][r] - mcur), p1 = __expf(acc_s[1][r] - mcur);
      float p2 = __expf(acc_s[2][r] - mcur), p3 = __expf(acc_s[3][r] - mcur);
      float ls = (p0 + p1) + (p2 + p3);
#pragma unroll
      for (int o = 1; o < 16; o <<= 1) ls += __shfl_xor(ls, o);
      lreg[r] += ls;
      int prow = (w * 16 + quad * 4 + r) * 72 + m16;
      kb16[prow + 0]  = f2bf(p0);
      kb16[prow + 16] = f2bf(p1);
      kb16[prow + 32] = f2bf(p2);
      kb16[prow + 48] = f2bf(p3);
    }
    __syncthreads();
#pragma unroll
    for (int kc = 0; kc < 64; kc += 32){
      bf16x8 a = *(const bf16x8*)(kb16 + (w * 16 + m16) * 72 + kc + quad * 8);
#pragma unroll
      for (int ni = 0; ni < 4; ni++){
        bf16x8 b = *(const bf16x8*)(vt16 + (ni * 16 + m16) * 72 + kc + quad * 8);
        acc_o[ni] = __builtin_amdgcn_mfma_f32_16x16x32_bf16(a, b, acc_o[ni], 0, 0, 0);
      }
    }
  }
#pragma unroll
  for (int r = 0; r < 4; r++){
    int im = lt * 64 + w * 16 + quad * 4 + r;
    size_t base = ((size_t)h * NCH + ch) * MLM + im;
#pragma unroll
    for (int ni = 0; ni < 4; ni++)
      pacc[base * HD_ + ni * 16 + m16] = acc_o[ni][r];
    if (m16 == 0){
      pml[base * 2]     = mreg[r];
      pml[base * 2 + 1] = lreg[r];
    }
  }
}

__global__ __launch_bounds__(64) void a3v_combine_kernel(
    const float* __restrict__ pacc, const float* __restrict__ pml,
    float* __restrict__ t1){
  const int im = blockIdx.x, h = blockIdx.y, lane = threadIdx.x;
  float M = -3.0e38f;
  for (int c = 0; c < NCH; c++)
    M = fmaxf(M, pml[(((size_t)h * NCH + c) * MLM + im) * 2]);
  float accv = 0.f, L = 0.f;
  for (int c = 0; c < NCH; c++){
    size_t base = ((size_t)h * NCH + c) * MLM + im;
    float mc = pml[base * 2], lc = pml[base * 2 + 1];
    float w = __expf(mc - M);
    accv += w * pacc[base * HD_ + lane];
    L += w * lc;
  }
  t1[((size_t)h * MLM + im) * HD_ + lane] = accv / L;
}

// ---------------- t2^T = (z @ t1)^T, bf16 [h][d][im] ----------------
__global__ __launch_bounds__(256) void zt1_kernel(
    const float* __restrict__ z, const float* __restrict__ t1,
    unsigned short* __restrict__ t2t){
  const int h = blockIdx.y;
  const int t = threadIdx.x;
  const int d = t & 63, ri = t >> 6;
  const int im = blockIdx.x * 4 + ri;
  const float* zr = z + ((size_t)h * MLM + im) * MLM;
  const float* t1h = t1 + (size_t)h * MLM * HD_;
  float acc = 0.f;
#pragma unroll 8
  for (int kk = 0; kk < MLM; kk++) acc += zr[kk] * t1h[(size_t)kk * HD_ + d];
  t2t[((size_t)h * HD_ + d) * MLM + im] = f2bf(acc);
}

// ---------------- out tile MFMA: 64 tokens x 1 head per block ----------------
// 1D grid, h = bid&7 (head->XCD pinning).
__global__ __launch_bounds__(256) void out_tile_kernel(
    const unsigned short* __restrict__ q16, const unsigned short* __restrict__ klh,
    const unsigned short* __restrict__ t2t, const unsigned short* __restrict__ v16,
    const float* __restrict__ resw, unsigned short* __restrict__ outh){
  __shared__ __align__(16) unsigned short smem[64 * 72 * 2 + 64 * 264];
  unsigned short* qs16 = smem;                 // 64 x 72
  unsigned short* kb16 = smem + 64 * 72;       // 64 x 72 (kl chunks, t2t chunks)
  unsigned short* Ps   = smem + 64 * 72 * 2;   // 64 x 264 (P bf16; later O f32 + v tile)
  const int bid = blockIdx.x;
  const int h = bid & 7, tile = bid >> 3;
  const int n0 = PADR + tile * 64;
  const int t = threadIdx.x;
  const int lane = t & 63, w = t >> 6;
  const int m16 = lane & 15, quad = lane >> 4;

  {
    const unsigned short* qh = q16 + (size_t)h * NP_ * HD_;
    for (int idx = t; idx < 512; idx += 256){
      int row = idx >> 3, off = (idx & 7) * 8;
      int n = n0 + row;
      uint4 val = {0u, 0u, 0u, 0u};
      if (n < NP_) val = *(const uint4*)(qh + (size_t)n * HD_ + off);
      *(uint4*)(qs16 + row * 72 + off) = val;
    }
  }
  f32x4 z4 = {0.f, 0.f, 0.f, 0.f};
  f32x4 acc_s[16];
#pragma unroll
  for (int i = 0; i < 16; i++) acc_s[i] = z4;
  const unsigned short* klg = klh + (size_t)h * MLM * HD_;
  for (int m = 0; m < 4; m++){
    __syncthreads();
    for (int idx = t; idx < 512; idx += 256){
      int row = idx >> 3, off = (idx & 7) * 8;
      *(uint4*)(kb16 + row * 72 + off) =
          *(const uint4*)(klg + (size_t)(m * 64 + row) * HD_ + off);
    }
    __syncthreads();
#pragma unroll
    for (int kc = 0; kc < 64; kc += 32){
      bf16x8 a = *(const bf16x8*)(qs16 + (w * 16 + m16) * 72 + kc + quad * 8);
#pragma unroll
      for (int ni = 0; ni < 4; ni++){
        bf16x8 b = *(const bf16x8*)(kb16 + (ni * 16 + m16) * 72 + kc + quad * 8);
        acc_s[m * 4 + ni] = __builtin_amdgcn_mfma_f32_16x16x32_bf16(a, b, acc_s[m * 4 + ni], 0, 0, 0);
      }
    }
  }
  __syncthreads();
#pragma unroll
  for (int r = 0; r < 4; r++){
    float mx = acc_s[0][r];
#pragma unroll
    for (int mc = 1; mc < 16; mc++) mx = fmaxf(mx, acc_s[mc][r]);
#pragma unroll
    for (int o = 1; o < 16; o <<= 1) mx = fmaxf(mx, __shfl_xor(mx, o));
    float p[16]; float sum = 0.f;
#pragma unroll
    for (int mc = 0; mc < 16; mc++){ p[mc] = __expf(acc_s[mc][r] - mx); sum += p[mc]; }
#pragma unroll
    for (int o = 1; o < 16; o <<= 1) sum += __shfl_xor(sum, o);
    float inv = 1.f / sum;
    int prow = (w * 16 + quad * 4 + r) * 264;
#pragma unroll
    for (int mc = 0; mc < 16; mc++)
      Ps[prow + (mc >> 2) * 64 + (mc & 3) * 16 + m16] = f2bf(p[mc] * inv);
  }
  f32x4 acc_o[4] = {z4, z4, z4, z4};
  const unsigned short* t2g = t2t + (size_t)h * HD_ * MLM;
  for (int ch = 0; ch < 4; ch++){
    __syncthreads();
    {
      int row = t >> 2, c8 = (t & 3) * 16;
      const unsigned short* src = t2g + (size_t)row * MLM + ch * 64 + c8;
      *(uint4*)(kb16 + row * 72 + c8)     = *(const uint4*)src;
      *(uint4*)(kb16 + row * 72 + c8 + 8) = *(const uint4*)(src + 8);
    }
    __syncthreads();
#pragma unroll
    for (int kc = 0; kc < 64; kc += 32){
      bf16x8 a = *(const bf16x8*)(Ps + (w * 16 + m16) * 264 + ch * 64 + kc + quad * 8);
#pragma unroll
      for (int ni = 0; ni < 4; ni++){
        bf16x8 b = *(const bf16x8*)(kb16 + (ni * 16 + m16) * 72 + kc + quad * 8);
        acc_o[ni] = __builtin_amdgcn_mfma_f32_16x16x32_bf16(a, b, acc_o[ni], 0, 0, 0);
      }
    }
  }
  __syncthreads();
  float* Obuf = (float*)Ps;                          // 64 x 66 f32
  unsigned short* vtile = (unsigned short*)(Obuf + 64 * 66);  // 96 x 72 bf16
#pragma unroll
  for (int r = 0; r < 4; r++){
    int row = w * 16 + quad * 4 + r;
#pragma unroll
    for (int ni = 0; ni < 4; ni++)
      Obuf[row * 66 + ni * 16 + m16] = acc_o[ni][r];
  }
  {
    const unsigned short* vh = v16 + (size_t)h * NP_ * HD_;
    for (int idx = t; idx < 768; idx += 256){
      int row = idx >> 3, off = (idx & 7) * 8;
      int nn = n0 - 16 + row;
      uint4 val = {0u, 0u, 0u, 0u};
      if (nn < NP_) val = *(const uint4*)(vh + (size_t)nn * HD_ + off);
      *(uint4*)(vtile + row * 72 + off) = val;
    }
  }
  __syncthreads();
  float wreg[33];
  {
    const float* wr = resw + h * 33;
#pragma unroll
    for (int kk = 0; kk < 33; kk++) wreg[kk] = wr[kk];
  }
  const int ty = t >> 4, tx = t & 15;
#pragma unroll
  for (int i = 0; i < 4; i++){
    int lrow = ty * 4 + i;
    float c0v = 0.f, c1v = 0.f, c2v = 0.f, c3v = 0.f;
    for (int kk = 0; kk < 33; kk++){
      uint2 uv = *(const uint2*)(vtile + (lrow + kk) * 72 + tx * 4);
      float wv = wreg[kk];
      c0v += __uint_as_float(uv.x << 16) * wv;
      c1v += __uint_as_float(uv.x & 0xffff0000u) * wv;
      c2v += __uint_as_float(uv.y << 16) * wv;
      c3v += __uint_as_float(uv.y & 0xffff0000u) * wv;
    }
    int trow = tile * 64 + lrow;
    if (trow < NTOK){
      const float* orow = Obuf + lrow * 66 + tx * 4;
      unsigned long long pk =
          (unsigned long long)f2bf(orow[0] + c0v)
        | ((unsigned long long)f2bf(orow[1] + c1v) << 16)
        | ((unsigned long long)f2bf(orow[2] + c2v) << 32)
        | ((unsigned long long)f2bf(orow[3] + c3v) << 48);
      *(unsigned long long*)(outh + (size_t)trow * D_ + h * HD_ + tx * 4) = pk;
    }
  }
}

// ---------------- proj MFMA: h += outh @ out_wt^T + bias ----------------
__global__ __launch_bounds__(256) void proj_mfma_kernel(
    const unsigned short* __restrict__ A, const unsigned short* __restrict__ Bt,
    const float* __restrict__ bias, float* __restrict__ h){
  __shared__ unsigned short As[128 * 72], Bs[128 * 72];
  f32x4 z4 = {0.f, 0.f, 0.f, 0.f};
  f32x4 acc[4][4];
#pragma unroll
  for (int i = 0; i < 4; i++)
#pragma unroll
    for (int j = 0; j < 4; j++) acc[i][j] = z4;
  const int bm = blockIdx.x * 128, bn = blockIdx.y * 128;
  mfma_tile128(A, NTOK, bm, Bt, bn, D_, acc, As, Bs);
  const int lane = threadIdx.x & 63, wave = threadIdx.x >> 6;
  const int wr = wave >> 1, wc = wave & 1;
  const int m16 = lane & 15, quad = lane >> 4;
#pragma unroll
  for (int mi = 0; mi < 4; mi++)
#pragma unroll
    for (int ni = 0; ni < 4; ni++){
      int col = bn + wc * 64 + ni * 16 + m16;
      float bv = bias[col];
#pragma unroll
      for (int r = 0; r < 4; r++){
        int row = bm + wr * 64 + mi * 16 + quad * 4 + r;
        if (row < NTOK) h[(size_t)row * D_ + col] += acc[mi][ni][r] + bv;
      }
    }
}

// ---------------- PPEG ----------------
__global__ __launch_bounds__(512) void ppeg_combine_kernel(
    const float* __restrict__ w7, const float* __restrict__ b7,
    const float* __restrict__ w5, const float* __restrict__ b5,
    const float* __restrict__ w3, const float* __restrict__ b3,
    float* __restrict__ wcomb, float* __restrict__ bcomb){
  const int c = threadIdx.x;
#pragma unroll
  for (int i = 0; i < 7; i++){
#pragma unroll
    for (int j = 0; j < 7; j++){
      int di = i - 3, dj = j - 3;
      float wv = w7[(size_t)c * 49 + i * 7 + j];
      if (di >= -2 && di <= 2 && dj >= -2 && dj <= 2)
        wv += w5[(size_t)c * 25 + (di + 2) * 5 + (dj + 2)];
      if (di >= -1 && di <= 1 && dj >= -1 && dj <= 1)
        wv += w3[(size_t)c * 9 + (di + 1) * 3 + (dj + 1)];
      if (di == 0 && dj == 0) wv += 1.f;
      wcomb[(size_t)(i * 7 + j) * 512 + c] = wv;
    }
  }
  bcomb[c] = b7[c] + b5[c] + b3[c];
}

// y-banded XCD map: xcd = bid&7 owns rows [xcd*18, xcd*18+18); within a band
// the rolling 7-row halo window (~1.4MB) stays L2-resident.
__global__ __launch_bounds__(512) void ppeg_conv_kernel(
    const float* __restrict__ h, const float* __restrict__ wcomb,
    const float* __restrict__ bcomb, float* __restrict__ h2){
  const int c = threadIdx.x;
  const int bid = blockIdx.x;
  const int xcd = bid & 7;
  const int idx = bid >> 3;          // 0..323
  const int y = xcd * 18 + idx / 18;
  const int x0 = (idx % 18) * 8;
  float wc[49];
#pragma unroll
  for (int kk = 0; kk < 49; kk++) wc[kk] = wcomb[(size_t)kk * 512 + c];
  float acc[8];
  const float bv = bcomb[c];
#pragma unroll
  for (int p = 0; p < 8; p++) acc[p] = bv;
#pragma unroll
  for (int i = 0; i < 7; i++){
    const int yy = y + i - 3;
    if (yy < 0 || yy >= HHW) continue;
    const float* hrow = h + (size_t)(1 + yy * HHW) * D_ + c;
    float line[14];
#pragma unroll
    for (int j = 0; j < 14; j++){
      const int xx = x0 + j - 3;
      line[j] = (xx >= 0 && xx < HHW) ? hrow[(size_t)xx * D_] : 0.f;
    }
#pragma unroll
    for (int p = 0; p < 8; p++)
#pragma unroll
      for (int j = 0; j < 7; j++)
        acc[p] += line[p + j] * wc[i * 7 + j];
  }
#pragma unroll
  for (int p = 0; p < 8; p++)
    h2[(size_t)(1 + y * HHW + x0 + p) * D_ + c] = acc[p];
}

// ---------------- final ----------------
__global__ __launch_bounds__(512) void final_kernel(
    const float* __restrict__ h, const float* __restrict__ w,
    const float* __restrict__ b, const float* __restrict__ fc3w,
    const float* __restrict__ fc3b, float* __restrict__ out){
  __shared__ float vec[512];
  __shared__ float s8[8];
  __shared__ float lg[4];
  const int t = threadIdx.x;
  float x = h[t];
  float v = waveSumF(x);
  if ((t & 63) == 0) s8[t >> 6] = v;
  __syncthreads();
  float sum = 0.f;
#pragma unroll
  for (int i = 0; i < 8; i++) sum += s8[i];
  float mu = sum * (1.f / 512.f);
  __syncthreads();
  float d = x - mu;
  v = waveSumF(d * d);
  if ((t & 63) == 0) s8[t >> 6] = v;
  __syncthreads();
  float var = 0.f;
#pragma unroll
  for (int i = 0; i < 8; i++) var += s8[i];
  var *= (1.f / 512.f);
  float rs = rsqrtf(var + 1e-5f);
  vec[t] = d * rs * w[t] + b[t];
  __syncthreads();
  if (t < 4){
    float acc = fc3b[t];
    for (int kk = 0; kk < 512; kk++) acc += vec[kk] * fc3w[kk * 4 + t];
    lg[t] = acc;
  }
  __syncthreads();
  if (t == 0){
    float m = fmaxf(fmaxf(lg[0], lg[1]), fmaxf(lg[2], lg[3]));
    float e[4], se = 0.f;
#pragma unroll
    for (int i = 0; i < 4; i++){ e[i] = __expf(lg[i] - m); se += e[i]; }
    int am = 0; float bm = lg[0];
#pragma unroll
    for (int i = 1; i < 4; i++) if (lg[i] > bm){ bm = lg[i]; am = i; }
#pragma unroll
    for (int i = 0; i < 4; i++){ out[i] = lg[i]; out[4 + i] = e[i] / se; }
    out[8] = (float)am;
  }
}

// ---------------------------------------------------------------------------
extern "C" void kernel_launch(void* const* d_in, const int* in_sizes, int n_in,
                              void* d_out, int out_size, void* d_ws, size_t ws_size,
                              hipStream_t stream) {
  const float* x       = (const float*)d_in[0];
  const float* fc1_w   = (const float*)d_in[1];
  const float* fc1_b   = (const float*)d_in[2];
  const float* cls_tok = (const float*)d_in[3];
  const float* l1_nw   = (const float*)d_in[4];
  const float* l1_nb   = (const float*)d_in[5];
  const float* l1_qkvw = (const float*)d_in[6];
  const float* l1_outw = (const float*)d_in[7];
  const float* l1_outb = (const float*)d_in[8];
  const float* l1_resw = (const float*)d_in[9];
  const float* ppeg_w7 = (const float*)d_in[10];
  const float* ppeg_b7 = (const float*)d_in[11];
  const float* ppeg_w5 = (const float*)d_in[12];
  const float* ppeg_b5 = (const float*)d_in[13];
  const float* ppeg_w3 = (const float*)d_in[14];
  const float* ppeg_b3 = (const float*)d_in[15];
  const float* l2_nw   = (const float*)d_in[16];
  const float* l2_nb   = (const float*)d_in[17];
  const float* l2_qkvw = (const float*)d_in[18];
  const float* l2_outw = (const float*)d_in[19];
  const float* l2_outb = (const float*)d_in[20];
  const float* l2_resw = (const float*)d_in[21];
  const float* norm_w  = (const float*)d_in[22];
  const float* norm_b  = (const float*)d_in[23];
  const float* fc3_w   = (const float*)d_in[24];
  const float* fc3_b   = (const float*)d_in[25];

  // workspace layout (float units)
  float* W = (float*)d_ws;
  size_t o = 0;
  float* hbuf = W + o; o += (size_t)NTOK * D_;
  float* xp   = W + o; o += (size_t)NP_ * D_;   // xph / pacc+pml / outh
  float* qb   = W + o; o += (size_t)NH_ * NP_ * HD_;   // bf16 q; also Ah pre-layer
  float* kb   = W + o; o += (size_t)NH_ * NP_ * HD_;   // bf16 k
  float* vb   = W + o; o += (size_t)NH_ * NP_ * HD_;   // bf16 v
  float* qlb  = W + o; o += (size_t)NH_ * MLM * HD_;
  float* klb  = W + o; o += (size_t)NH_ * MLM * HD_;
  float* a2b  = W + o; o += (size_t)NH_ * MLM * MLM;
  float* zfin = W + o; o += (size_t)NH_ * MLM * MLM;   // final z fp32 (zt1 input)
  float* t1b  = W + o; o += (size_t)NH_ * MLM * HD_;
  float* t2r  = W + o; o += (size_t)NH_ * MLM * HD_;   // t2t bf16 lives here
  float* scalf = W + o; o += 16;
  float* wcomb = W + o; o += 49 * 512;
  float* bcomb = W + o; o += 512;
  unsigned short* fc1_wt  = (unsigned short*)(W + o); o += (size_t)D_ * E_ / 2;
  unsigned short* qkv_wt1 = (unsigned short*)(W + o); o += (size_t)1536 * D_ / 2;
  unsigned short* qkv_wt2 = (unsigned short*)(W + o); o += (size_t)1536 * D_ / 2;
  unsigned short* out_wt1 = (unsigned short*)(W + o); o += (size_t)D_ * D_ / 2;
  unsigned short* out_wt2 = (unsigned short*)(W + o); o += (size_t)D_ * D_ / 2;
  unsigned short* qlh = (unsigned short*)(W + o); o += (size_t)NH_ * MLM * HD_ / 2;
  unsigned short* klh = (unsigned short*)(W + o); o += (size_t)NH_ * MLM * HD_ / 2;
  // pinv split-bf16 arrays: 18 x [NH][256][256] ushorts
  const size_t HM = (size_t)NH_ * MLM * MLM;
  unsigned short* usp = (unsigned short*)(W + o); o += 18 * HM / 2;
  unsigned short* a2sh  = usp; usp += HM;
  unsigned short* a2sl  = usp; usp += HM;
  unsigned short* tah_s = usp; usp += HM;
  unsigned short* tal_s = usp; usp += HM;
  unsigned short* tath_s = usp; usp += HM;
  unsigned short* tatl_s = usp; usp += HM;
  unsigned short* tbth_s = usp; usp += HM;
  unsigned short* tbtl_s = usp; usp += HM;
  unsigned short* tcth_s = usp; usp += HM;
  unsigned short* tctl_s = usp; usp += HM;
  unsigned short* zsh[2], *zsl[2], *zsth[2], *zstl[2];
  for (int s = 0; s < 2; s++){
    zsh[s]  = usp; usp += HM;
    zsl[s]  = usp; usp += HM;
    zsth[s] = usp; usp += HM;
    zstl[s] = usp; usp += HM;
  }
  float* hbuf2 = W + o; o += (size_t)NTOK * D_;       // ppeg ping-pong target

  unsigned short* xph = (unsigned short*)xp;
  float* pacc = xp;
  float* pml  = xp + (size_t)NH_ * NCH * MLM * HD_;
  unsigned short* outh = (unsigned short*)xp;
  unsigned short* Ah  = (unsigned short*)qb;
  unsigned short* q16 = (unsigned short*)qb;
  unsigned short* k16 = (unsigned short*)kb;
  unsigned short* v16 = (unsigned short*)vb;
  unsigned short* t2t = (unsigned short*)t2r;

  // ---- weight prep (once per launch) ----
  wtrans_kernel<<<dim3(E_ / 32, D_ / 32), dim3(32, 8), 0, stream>>>(fc1_w, fc1_wt, E_, D_);
  wtrans_kernel<<<dim3(D_ / 32, 1536 / 32), dim3(32, 8), 0, stream>>>(l1_qkvw, qkv_wt1, D_, 1536);
  wtrans_kernel<<<dim3(D_ / 32, 1536 / 32), dim3(32, 8), 0, stream>>>(l2_qkvw, qkv_wt2, D_, 1536);
  wtrans_kernel<<<dim3(D_ / 32, D_ / 32), dim3(32, 8), 0, stream>>>(l1_outw, out_wt1, D_, D_);
  wtrans_kernel<<<dim3(D_ / 32, D_ / 32), dim3(32, 8), 0, stream>>>(l2_outw, out_wt2, D_, D_);
  ppeg_combine_kernel<<<1, 512, 0, stream>>>(ppeg_w7, ppeg_b7, ppeg_w5, ppeg_b5,
                                             ppeg_w3, ppeg_b3, wcomb, bcomb);

  // ---- fc1 (maxpool -> bf16 -> MFMA 128-tile) ----
  pool_bf16_kernel<<<20480, 256, 0, stream>>>(x, Ah);
  fc1_mfma_kernel<<<dim3(160, 4), 256, 0, stream>>>(Ah, fc1_wt, fc1_b, hbuf);
  cls_kernel<<<2, 256, 0, stream>>>(cls_tok, hbuf);

  auto run_layer = [&](float* hcur, const float* nw, const float* nb,
                       const unsigned short* qkvwt, const unsigned short* outwt,
                       const float* outb, const float* resw){
    ln_pad_kernel<<<NP_ / 4, 256, 0, stream>>>(hcur, nw, nb, xph);
    qkv_mfma_kernel<<<dim3(164, 12), 256, 0, stream>>>(xph, qkvwt, q16, k16, v16);
    landmark_kernel<<<dim3(64, 8), 256, 0, stream>>>(q16, k16, qlb, klb, qlh, klh);
    a2_kernel<<<dim3(256, 8), 256, 0, stream>>>(qlb, klb, a2b, a2sh, a2sl);
    pinv_scale_kernel<<<8, 256, 0, stream>>>(a2b, scalf);
    pinv_init_kernel<<<dim3(256, 8), 256, 0, stream>>>(a2b, scalf,
        zsh[0], zsl[0], zsth[0], zstl[0]);
    int c = 0;
    for (int it = 0; it < 6; it++){
      // ta = a2 @ z                  (RM for A-use; -ta^T for B-use)
      bmm256_split_kernel<<<512, 256, 0, stream>>>(
          a2sh, a2sl, zsth[c], zstl[c], 0.f, 1.f,
          tah_s, tal_s, tath_s, tatl_s, nullptr, 0x8000u);
      // tb = ta @ (7I - ta)          (-tb^T only)
      bmm256_split_kernel<<<512, 256, 0, stream>>>(
          tah_s, tal_s, tath_s, tatl_s, 7.f, 1.f,
          nullptr, nullptr, tbth_s, tbtl_s, nullptr, 0x8000u);
      // tc = ta @ (15I - tb)         (-tc^T only)
      bmm256_split_kernel<<<512, 256, 0, stream>>>(
          tah_s, tal_s, tbth_s, tbtl_s, 15.f, 1.f,
          nullptr, nullptr, tcth_s, tctl_s, nullptr, 0x8000u);
      // z' = 0.25 * z @ (13I - tc)   (RM + +z'^T; fp32 on last iter)
      bmm256_split_kernel<<<512, 256, 0, stream>>>(
          zsh[c], zsl[c], tcth_s, tctl_s, 13.f, 0.25f,
          zsh[c ^ 1], zsl[c ^ 1], zsth[c ^ 1], zstl[c ^ 1],
          (it == 5) ? zfin : nullptr, 0u);
      c ^= 1;
    }
    a3v_part_kernel<<<NCH * 32, 256, 0, stream>>>(qlh, k16, v16, pacc, pml);
    a3v_combine_kernel<<<dim3(256, 8), 64, 0, stream>>>(pacc, pml, t1b);
    zt1_kernel<<<dim3(64, 8), 256, 0, stream>>>(zfin, t1b, t2t);
    out_tile_kernel<<<325 * 8, 256, 0, stream>>>(q16, klh, t2t, v16, resw, outh);
    proj_mfma_kernel<<<dim3(163, 4), 256, 0, stream>>>(outh, outwt, outb, hcur);
  };

  run_layer(hbuf, l1_nw, l1_nb, qkv_wt1, out_wt1, l1_outb, l1_resw);
  // PPEG: conv writes rows 1.. of hbuf2 directly; cls row copied
  ppeg_conv_kernel<<<2592, 512, 0, stream>>>(hbuf, wcomb, bcomb, hbuf2);
  row0_copy_kernel<<<2, 256, 0, stream>>>(hbuf, hbuf2);
  run_layer(hbuf2, l2_nw, l2_nb, qkv_wt2, out_wt2, l2_outb, l2_resw);
  final_kernel<<<1, 512, 0, stream>>>(hbuf2, norm_w, norm_b, fc3_w, fc3_b, (float*)d_out);
}